// Round 3
// baseline (568.951 us; speedup 1.0000x reference)
//
#include <hip/hip_runtime.h>

#define N_NODES 50000
#define N_EDGES 800000
#define F_INK   256
#define HC      512   // H*C = 8*64
#define OUT_C   40
#define OUT_P   48    // padded cols for GEMM2
#define NEG     0.2f

typedef short short8 __attribute__((ext_vector_type(8)));
typedef float f32x4 __attribute__((ext_vector_type(4)));

__device__ __forceinline__ float bf2f(unsigned short u) {
    union { unsigned int i; float f; } v; v.i = ((unsigned int)u) << 16; return v.f;
}
__device__ __forceinline__ unsigned short f2bf(float f) {
    union { float f; unsigned int i; } v; v.f = f;
    unsigned int x = v.i;
    return (unsigned short)((x + 0x7fffu + ((x >> 16) & 1u)) >> 16);
}
__device__ __forceinline__ float bflo(unsigned int u) {
    union { unsigned int i; float f; } v; v.i = u << 16; return v.f;
}
__device__ __forceinline__ float bfhi(unsigned int u) {
    union { unsigned int i; float f; } v; v.i = u & 0xffff0000u; return v.f;
}
// int64-vs-int32 edge_index probe: for int64 the high words of src[0..2] are 0.
__device__ __forceinline__ bool ei_is64(const int* ei) {
    return ei[1] == 0 && ei[3] == 0 && ei[5] == 0;
}

// ---------------- input canonicalization: fp32-or-bf16 -> bf16 ----------------
// Probe: sample up to 64 spread words; a bf16 buffer's low halfwords are real
// values (exp field <= ~130 for N(0,sigma<=1) data); an fp32 buffer's low
// halfwords are mantissa bits with uniform exponent field -> hit near-certain.
__global__ void canon_k(const void* __restrict__ in_, unsigned short* __restrict__ out, long n) {
    const unsigned int* inw = (const unsigned int*)in_;
    __shared__ int s_is32;
    if (threadIdx.x < 64) {
        long nw = n >> 1;                  // words safe to read under BOTH interpretations
        long samples = nw < 64 ? nw : 64;
        int hit = 0;
        if ((long)threadIdx.x < samples) {
            long step = nw / samples; if (step < 1) step = 1;
            unsigned int w = inw[(long)threadIdx.x * step];
            unsigned int e = (w >> 7) & 0xffu;   // exponent field of LOW bf16 half
            hit = (e > 140u) ? 1 : 0;
        }
        unsigned long long m = __ballot(hit);
        if (threadIdx.x == 0) s_is32 = (m != 0ull);
    }
    __syncthreads();
    bool is32 = (s_is32 != 0);
    long i = (long)blockIdx.x * blockDim.x + threadIdx.x;
    long stride = (long)gridDim.x * blockDim.x;
    if (is32) {
        const float* f = (const float*)in_;
        for (; i < n; i += stride) out[i] = f2bf(f[i]);
    } else {
        const unsigned short* s = (const unsigned short*)in_;
        for (; i < n; i += stride) out[i] = s[i];
    }
}

// ---------------- weight packing for MFMA B-operand ----------------
// B-frag layout (16x16x32): lane l (q=l>>4, n=l&15) holds B[k=q*8+j][n], j=0..7.
// Pack so each lane's 8 elems are contiguous: Wp[((s*4+q)*LD + n)*8 + j] = W[k][n], k=s*32+q*8+j.
__global__ void pack_w1(const unsigned short* __restrict__ W, unsigned short* __restrict__ Wp) {
    int t = blockIdx.x * 256 + threadIdx.x;
    if (t >= F_INK * HC) return;
    int k = t / HC, n = t % HC;
    int s = k >> 5, q = (k >> 3) & 3, j = k & 7;
    Wp[((((s << 2) + q) * HC + n) << 3) + j] = W[k * HC + n];
}
__global__ void pack_w2(const unsigned short* __restrict__ W, unsigned short* __restrict__ Wp) {
    int t = blockIdx.x * 256 + threadIdx.x;
    if (t >= HC * OUT_P) return;
    int k = t / OUT_P, n = t % OUT_P;
    int s = k >> 5, q = (k >> 3) & 3, j = k & 7;
    unsigned short v = (n < OUT_C) ? W[k * OUT_C + n] : (unsigned short)0;
    Wp[((((s << 2) + q) * OUT_P + n) << 3) + j] = v;
}

// ---------------- GEMM1: h1[N,512] = x[N,256] @ W1 (bf16 in, bf16 out) ----------------
__global__ __launch_bounds__(256) void gemm1_k(const unsigned short* __restrict__ x,
                                               const unsigned short* __restrict__ Wp,
                                               unsigned short* __restrict__ h1) {
    int w = threadIdx.x >> 6, lane = threadIdx.x & 63;
    int q = lane >> 4, l16 = lane & 15;
    int bm = blockIdx.x, bn = blockIdx.y;
    int row = bm * 64 + w * 16 + l16;
    int rowc = row < N_NODES ? row : N_NODES - 1;
    const unsigned short* xr = x + (size_t)rowc * F_INK;
    f32x4 acc[4];
#pragma unroll
    for (int t = 0; t < 4; t++) acc[t] = (f32x4){0.f, 0.f, 0.f, 0.f};
#pragma unroll
    for (int s = 0; s < F_INK / 32; s++) {
        short8 a = *reinterpret_cast<const short8*>(xr + s * 32 + q * 8);
#pragma unroll
        for (int t = 0; t < 4; t++) {
            int col = bn * 64 + t * 16 + l16;
            short8 b = *reinterpret_cast<const short8*>(Wp + ((((s << 2) + q) * HC + col) << 3));
            acc[t] = __builtin_amdgcn_mfma_f32_16x16x32_bf16(a, b, acc[t], 0, 0, 0);
        }
    }
    int orow = bm * 64 + w * 16 + q * 4;  // C/D: reg r of lane -> row (lane>>4)*4+r, col lane&15
#pragma unroll
    for (int t = 0; t < 4; t++) {
        int col = bn * 64 + t * 16 + l16;
#pragma unroll
        for (int r = 0; r < 4; r++) {
            int rr = orow + r;
            if (rr < N_NODES) h1[(size_t)rr * HC + col] = f2bf(acc[t][r]);
        }
    }
}

// ---------------- GEMM2: h2[N,40] = out1[N,512] @ W2 (bf16 in, fp32 out) ----------------
__global__ __launch_bounds__(256) void gemm2_k(const unsigned short* __restrict__ a_in,
                                               const unsigned short* __restrict__ Wp,
                                               float* __restrict__ h2) {
    int w = threadIdx.x >> 6, lane = threadIdx.x & 63;
    int q = lane >> 4, l16 = lane & 15;
    int bm = blockIdx.x;
    int row = bm * 64 + w * 16 + l16;
    int rowc = row < N_NODES ? row : N_NODES - 1;
    const unsigned short* ar = a_in + (size_t)rowc * HC;
    f32x4 acc[3];
#pragma unroll
    for (int t = 0; t < 3; t++) acc[t] = (f32x4){0.f, 0.f, 0.f, 0.f};
#pragma unroll
    for (int s = 0; s < HC / 32; s++) {
        short8 a = *reinterpret_cast<const short8*>(ar + s * 32 + q * 8);
#pragma unroll
        for (int t = 0; t < 3; t++) {
            int col = t * 16 + l16;
            short8 b = *reinterpret_cast<const short8*>(Wp + ((((s << 2) + q) * OUT_P + col) << 3));
            acc[t] = __builtin_amdgcn_mfma_f32_16x16x32_bf16(a, b, acc[t], 0, 0, 0);
        }
    }
    int orow = bm * 64 + w * 16 + q * 4;
#pragma unroll
    for (int t = 0; t < 3; t++) {
        int col = t * 16 + l16;
#pragma unroll
        for (int r = 0; r < 4; r++) {
            int rr = orow + r;
            if (rr < N_NODES && col < OUT_C) h2[(size_t)rr * OUT_C + col] = acc[t][r];
        }
    }
}

// ---------------- alpha1: as1/ad1[n,h] = <h1[n,h,:], a_src1/a_dst1[h,:]> ----------------
__global__ __launch_bounds__(256) void alpha1_k(const unsigned short* __restrict__ h1,
                                                const unsigned short* __restrict__ a_s,
                                                const unsigned short* __restrict__ a_d,
                                                float* __restrict__ as1, float* __restrict__ ad1) {
    int t = blockIdx.x * 256 + threadIdx.x;
    if (t >= N_NODES * 8) return;
    int n = t >> 3, h = t & 7;
    const unsigned short* hp = h1 + (size_t)n * HC + h * 64;
    const unsigned short* sp = a_s + h * 64;
    const unsigned short* dp = a_d + h * 64;
    float sa = 0.f, da = 0.f;
#pragma unroll
    for (int c = 0; c < 64; c++) {
        float hv = bf2f(hp[c]);
        sa += hv * bf2f(sp[c]);
        da += hv * bf2f(dp[c]);
    }
    as1[t] = sa;
    ad1[t] = da;
}

// ---------------- CSR build ----------------
__global__ void deg_init(int* __restrict__ deg) {
    int n = blockIdx.x * 256 + threadIdx.x;
    if (n < N_NODES) deg[n] = 1;  // self loop
}
__global__ void deg_count(const int* __restrict__ ei, int* __restrict__ deg) {
    int e = blockIdx.x * 256 + threadIdx.x;
    if (e >= N_EDGES) return;
    bool is64 = ei_is64(ei);
    int dst = is64 ? ei[2 * N_EDGES + 2 * e] : ei[N_EDGES + e];
    atomicAdd(&deg[dst], 1);
}
__global__ void scan_block(const int* __restrict__ deg, int* __restrict__ off, int* __restrict__ bsum) {
    __shared__ int s[256];
    int i = blockIdx.x * 256 + threadIdx.x;
    int v = (i < N_NODES) ? deg[i] : 0;
    s[threadIdx.x] = v;
    __syncthreads();
    for (int d = 1; d < 256; d <<= 1) {
        int t = (threadIdx.x >= d) ? s[threadIdx.x - d] : 0;
        __syncthreads();
        s[threadIdx.x] += t;
        __syncthreads();
    }
    if (i < N_NODES) off[i] = s[threadIdx.x] - v;
    if (threadIdx.x == 255) bsum[blockIdx.x] = s[255];
}
__global__ void scan_sums(const int* __restrict__ bsum, int* __restrict__ bscan, int* __restrict__ off, int nb) {
    __shared__ int s[256];
    int v = (threadIdx.x < nb) ? bsum[threadIdx.x] : 0;
    s[threadIdx.x] = v;
    __syncthreads();
    for (int d = 1; d < 256; d <<= 1) {
        int t = (threadIdx.x >= d) ? s[threadIdx.x - d] : 0;
        __syncthreads();
        s[threadIdx.x] += t;
        __syncthreads();
    }
    if (threadIdx.x < nb) bscan[threadIdx.x] = s[threadIdx.x] - v;
    if (threadIdx.x == 255) off[N_NODES] = s[255];
}
__global__ void scan_add(int* __restrict__ off, const int* __restrict__ bscan, int* __restrict__ cursor) {
    int i = blockIdx.x * 256 + threadIdx.x;
    if (i < N_NODES) {
        int v = off[i] + bscan[blockIdx.x];
        off[i] = v;
        cursor[i] = v;
    }
}
__global__ void scatter_self(int* __restrict__ cursor, int* __restrict__ srcs) {
    int n = blockIdx.x * 256 + threadIdx.x;
    if (n >= N_NODES) return;
    int pos = atomicAdd(&cursor[n], 1);
    srcs[pos] = n;
}
__global__ void scatter_edge(const int* __restrict__ ei, int* __restrict__ cursor, int* __restrict__ srcs) {
    int e = blockIdx.x * 256 + threadIdx.x;
    if (e >= N_EDGES) return;
    bool is64 = ei_is64(ei);
    int src = is64 ? ei[2 * e] : ei[e];
    int dst = is64 ? ei[2 * N_EDGES + 2 * e] : ei[N_EDGES + e];
    int pos = atomicAdd(&cursor[dst], 1);
    srcs[pos] = src;
}

// ---------------- layer-1 aggregation: one wave per dst node ----------------
// lane l owns channels [l*8, l*8+8) of the 512-wide row (head h = l>>3).
__global__ __launch_bounds__(256) void agg1_k(const unsigned short* __restrict__ h1,
                                              const float* __restrict__ as1,
                                              const float* __restrict__ ad1,
                                              const int* __restrict__ off,
                                              const int* __restrict__ srcs,
                                              const unsigned short* __restrict__ b1,
                                              unsigned short* __restrict__ out1) {
    int wid = blockIdx.x * 4 + (threadIdx.x >> 6);
    if (wid >= N_NODES) return;
    int lane = threadIdx.x & 63;
    int h = lane >> 3;
    float adv = ad1[wid * 8 + h];
    float acc0 = 0.f, acc1 = 0.f, acc2 = 0.f, acc3 = 0.f;
    float acc4 = 0.f, acc5 = 0.f, acc6 = 0.f, acc7 = 0.f;
    float sumw = 0.f;
    int e0 = off[wid], e1 = off[wid + 1];
    for (int e = e0; e < e1; e++) {
        int src = srcs[e];
        float lg = as1[src * 8 + h] + adv;
        lg = lg > 0.f ? lg : NEG * lg;
        float wgt = __expf(lg);  // no max-subtraction needed: logits are O(1)
        sumw += wgt;
        uint4 u = *(reinterpret_cast<const uint4*>(h1 + (size_t)src * HC) + lane);
        acc0 += wgt * bflo(u.x); acc1 += wgt * bfhi(u.x);
        acc2 += wgt * bflo(u.y); acc3 += wgt * bfhi(u.y);
        acc4 += wgt * bflo(u.z); acc5 += wgt * bfhi(u.z);
        acc6 += wgt * bflo(u.w); acc7 += wgt * bfhi(u.w);
    }
    float inv = 1.f / sumw;
    uint4 ub = *(reinterpret_cast<const uint4*>(b1) + lane);
    float o0 = fmaxf(acc0 * inv + bflo(ub.x), 0.f);
    float o1 = fmaxf(acc1 * inv + bfhi(ub.x), 0.f);
    float o2 = fmaxf(acc2 * inv + bflo(ub.y), 0.f);
    float o3 = fmaxf(acc3 * inv + bfhi(ub.y), 0.f);
    float o4 = fmaxf(acc4 * inv + bflo(ub.z), 0.f);
    float o5 = fmaxf(acc5 * inv + bfhi(ub.z), 0.f);
    float o6 = fmaxf(acc6 * inv + bflo(ub.w), 0.f);
    float o7 = fmaxf(acc7 * inv + bfhi(ub.w), 0.f);
    uint4 r;
    r.x = (unsigned int)f2bf(o0) | ((unsigned int)f2bf(o1) << 16);
    r.y = (unsigned int)f2bf(o2) | ((unsigned int)f2bf(o3) << 16);
    r.z = (unsigned int)f2bf(o4) | ((unsigned int)f2bf(o5) << 16);
    r.w = (unsigned int)f2bf(o6) | ((unsigned int)f2bf(o7) << 16);
    *(reinterpret_cast<uint4*>(out1 + (size_t)wid * HC) + lane) = r;
}

// ---------------- alpha2 ----------------
__global__ __launch_bounds__(256) void alpha2_k(const float* __restrict__ h2,
                                                const unsigned short* __restrict__ a_s2,
                                                const unsigned short* __restrict__ a_d2,
                                                float* __restrict__ as2, float* __restrict__ ad2) {
    int n = blockIdx.x * 256 + threadIdx.x;
    if (n >= N_NODES) return;
    const float* hp = h2 + (size_t)n * OUT_C;
    float sa = 0.f, da = 0.f;
#pragma unroll
    for (int j = 0; j < OUT_C; j++) {
        float v = hp[j];
        sa += v * bf2f(a_s2[j]);
        da += v * bf2f(a_d2[j]);
    }
    as2[n] = sa;
    ad2[n] = da;
}

// ---------------- layer-2 aggregation + log_softmax: one wave per dst (fp32 out) ----------
__global__ __launch_bounds__(256) void agg2_k(const float* __restrict__ h2,
                                              const float* __restrict__ as2,
                                              const float* __restrict__ ad2,
                                              const int* __restrict__ off,
                                              const int* __restrict__ srcs,
                                              const unsigned short* __restrict__ b2,
                                              float* __restrict__ outp) {
    int wid = blockIdx.x * 4 + (threadIdx.x >> 6);
    if (wid >= N_NODES) return;
    int lane = threadIdx.x & 63;
    bool act = lane < OUT_C;
    float adv = ad2[wid];
    float acc = 0.f, sumw = 0.f;
    int e0 = off[wid], e1 = off[wid + 1];
    for (int e = e0; e < e1; e++) {
        int src = srcs[e];
        float lg = as2[src] + adv;
        lg = lg > 0.f ? lg : NEG * lg;
        float wgt = __expf(lg);
        sumw += wgt;
        float v = act ? h2[(size_t)src * OUT_C + lane] : 0.f;
        acc += wgt * v;
    }
    float o = acc / sumw + (act ? bf2f(b2[lane]) : 0.f);
    float mval = act ? o : -1e30f;
#pragma unroll
    for (int m = 32; m >= 1; m >>= 1) mval = fmaxf(mval, __shfl_xor(mval, m, 64));
    float ex = act ? __expf(o - mval) : 0.f;
#pragma unroll
    for (int m = 32; m >= 1; m >>= 1) ex += __shfl_xor(ex, m, 64);
    float res = o - mval - __logf(ex);
    if (act) outp[(size_t)wid * OUT_C + lane] = res;   // fp32 output
}

extern "C" void kernel_launch(void* const* d_in, const int* in_sizes, int n_in,
                              void* d_out, int out_size, void* d_ws, size_t ws_size,
                              hipStream_t stream) {
    const void* x_raw  = d_in[0];
    const int*  ei     = (const int*)d_in[1];
    const void* W1_raw = d_in[2];
    const void* as1raw = d_in[3];
    const void* ad1raw = d_in[4];
    const void* b1_raw = d_in[5];
    const void* W2_raw = d_in[6];
    const void* as2raw = d_in[7];
    const void* ad2raw = d_in[8];
    const void* b2_raw = d_in[9];
    float* out = (float*)d_out;

    char* p = (char*)d_ws;
    auto alloc = [&](size_t bytes) -> char* {
        char* r = p;
        p += (bytes + 255) & ~(size_t)255;
        return r;
    };
    unsigned short* xc   = (unsigned short*)alloc((size_t)N_NODES * F_INK * 2);    // 25.6 MB
    unsigned short* w1c  = (unsigned short*)alloc((size_t)F_INK * HC * 2);
    unsigned short* w2c  = (unsigned short*)alloc((size_t)HC * OUT_C * 2);
    unsigned short* s1c  = (unsigned short*)alloc(512 * 2);
    unsigned short* d1c  = (unsigned short*)alloc(512 * 2);
    unsigned short* b1c  = (unsigned short*)alloc(512 * 2);
    unsigned short* s2c  = (unsigned short*)alloc(OUT_C * 2);
    unsigned short* d2c  = (unsigned short*)alloc(OUT_C * 2);
    unsigned short* b2c  = (unsigned short*)alloc(OUT_C * 2);
    unsigned short* h1   = (unsigned short*)alloc((size_t)N_NODES * HC * 2);       // 51.2 MB
    unsigned short* out1 = (unsigned short*)alloc((size_t)N_NODES * HC * 2);       // 51.2 MB
    float* h2   = (float*)alloc((size_t)N_NODES * OUT_C * 4);                      // 8 MB
    float* as1  = (float*)alloc((size_t)N_NODES * 8 * 4);
    float* ad1  = (float*)alloc((size_t)N_NODES * 8 * 4);
    float* as2  = (float*)alloc((size_t)N_NODES * 4);
    float* ad2  = (float*)alloc((size_t)N_NODES * 4);
    int* deg    = (int*)alloc((size_t)N_NODES * 4);
    int* off    = (int*)alloc((size_t)(N_NODES + 1) * 4);
    int* cursor = (int*)alloc((size_t)N_NODES * 4);
    int* srcs   = (int*)alloc((size_t)(N_EDGES + N_NODES) * 4);
    unsigned short* W1p = (unsigned short*)alloc((size_t)F_INK * HC * 2);
    unsigned short* W2p = (unsigned short*)alloc((size_t)HC * OUT_P * 2);
    int* bsum  = (int*)alloc(256 * 4);
    int* bscan = (int*)alloc(256 * 4);
    (void)ws_size; (void)in_sizes; (void)n_in; (void)out_size;

    const int NB = (N_NODES + 255) / 256;  // 196

    // canonicalize float inputs to bf16 (device-side dtype probe)
    canon_k<<<1024, 256, 0, stream>>>(x_raw, xc, (long)N_NODES * F_INK);
    canon_k<<<64, 256, 0, stream>>>(W1_raw, w1c, (long)F_INK * HC);
    canon_k<<<16, 256, 0, stream>>>(W2_raw, w2c, (long)HC * OUT_C);
    canon_k<<<1, 256, 0, stream>>>(as1raw, s1c, 512);
    canon_k<<<1, 256, 0, stream>>>(ad1raw, d1c, 512);
    canon_k<<<1, 256, 0, stream>>>(b1_raw, b1c, 512);
    canon_k<<<1, 256, 0, stream>>>(as2raw, s2c, OUT_C);
    canon_k<<<1, 256, 0, stream>>>(ad2raw, d2c, OUT_C);
    canon_k<<<1, 256, 0, stream>>>(b2_raw, b2c, OUT_C);

    pack_w1<<<(F_INK * HC + 255) / 256, 256, 0, stream>>>(w1c, W1p);
    pack_w2<<<(HC * OUT_P + 255) / 256, 256, 0, stream>>>(w2c, W2p);
    gemm1_k<<<dim3((N_NODES + 63) / 64, HC / 64), 256, 0, stream>>>(xc, W1p, h1);
    alpha1_k<<<(N_NODES * 8 + 255) / 256, 256, 0, stream>>>(h1, s1c, d1c, as1, ad1);
    deg_init<<<NB, 256, 0, stream>>>(deg);
    deg_count<<<(N_EDGES + 255) / 256, 256, 0, stream>>>(ei, deg);
    scan_block<<<NB, 256, 0, stream>>>(deg, off, bsum);
    scan_sums<<<1, 256, 0, stream>>>(bsum, bscan, off, NB);
    scan_add<<<NB, 256, 0, stream>>>(off, bscan, cursor);
    scatter_self<<<NB, 256, 0, stream>>>(cursor, srcs);
    scatter_edge<<<(N_EDGES + 255) / 256, 256, 0, stream>>>(ei, cursor, srcs);
    agg1_k<<<(N_NODES + 3) / 4, 256, 0, stream>>>(h1, as1, ad1, off, srcs, b1c, out1);
    gemm2_k<<<(N_NODES + 63) / 64, 256, 0, stream>>>(out1, W2p, h2);
    alpha2_k<<<NB, 256, 0, stream>>>(h2, s2c, d2c, as2, ad2);
    agg2_k<<<(N_NODES + 3) / 4, 256, 0, stream>>>(h2, as2, ad2, off, srcs, b2c, out);
}

// Round 4
// 434.810 us; speedup vs baseline: 1.3085x; 1.3085x over previous
//
#include <hip/hip_runtime.h>

#define N_NODES 50000
#define N_EDGES 800000
#define F_INK   256
#define HC      512   // H*C = 8*64
#define OUT_C   40
#define OUT_P   48    // padded cols for GEMM2
#define NEG     0.2f

typedef short short8 __attribute__((ext_vector_type(8)));
typedef float f32x4 __attribute__((ext_vector_type(4)));

__device__ __forceinline__ float bf2f(unsigned short u) {
    union { unsigned int i; float f; } v; v.i = ((unsigned int)u) << 16; return v.f;
}
__device__ __forceinline__ unsigned short f2bf(float f) {
    union { float f; unsigned int i; } v; v.f = f;
    unsigned int x = v.i;
    return (unsigned short)((x + 0x7fffu + ((x >> 16) & 1u)) >> 16);
}
__device__ __forceinline__ float bflo(unsigned int u) {
    union { unsigned int i; float f; } v; v.i = u << 16; return v.f;
}
__device__ __forceinline__ float bfhi(unsigned int u) {
    union { unsigned int i; float f; } v; v.i = u & 0xffff0000u; return v.f;
}
// int64-vs-int32 edge_index probe: for int64 the high words of src[0..2] are 0.
__device__ __forceinline__ bool ei_is64(const int* ei) {
    return ei[1] == 0 && ei[3] == 0 && ei[5] == 0;
}
__device__ __forceinline__ float lrelu(float x) { return x > 0.f ? x : NEG * x; }

// ---------------- weight packing (fp32 in, packed bf16 out) ----------------
// B-frag layout (16x16x32): lane l (q=l>>4, n=l&15) holds B[k=q*8+j][n], j=0..7.
// Wp[((s*4+q)*LD + n)*8 + j] = W[k][n], k=s*32+q*8+j.
__global__ void pack_w1(const float* __restrict__ W, unsigned short* __restrict__ Wp) {
    int t = blockIdx.x * 256 + threadIdx.x;
    if (t >= F_INK * HC) return;
    int k = t / HC, n = t % HC;
    int s = k >> 5, q = (k >> 3) & 3, j = k & 7;
    Wp[((((s << 2) + q) * HC + n) << 3) + j] = f2bf(W[k * HC + n]);
}
__global__ void pack_w2(const float* __restrict__ W, unsigned short* __restrict__ Wp) {
    int t = blockIdx.x * 256 + threadIdx.x;
    if (t >= HC * OUT_P) return;
    int k = t / OUT_P, n = t % OUT_P;
    int s = k >> 5, q = (k >> 3) & 3, j = k & 7;
    unsigned short v = (n < OUT_C) ? f2bf(W[k * OUT_C + n]) : (unsigned short)0;
    Wp[((((s << 2) + q) * OUT_P + n) << 3) + j] = v;
}

// ---------------- canon small fp32 arrays -> bf16, + deg init ----------------
__global__ void canon_small(const float* __restrict__ s1, const float* __restrict__ d1,
                            const float* __restrict__ b1, const float* __restrict__ s2,
                            const float* __restrict__ d2, const float* __restrict__ b2,
                            unsigned short* __restrict__ s1c, unsigned short* __restrict__ d1c,
                            unsigned short* __restrict__ b1c, unsigned short* __restrict__ s2c,
                            unsigned short* __restrict__ d2c, unsigned short* __restrict__ b2c,
                            int* __restrict__ deg) {
    int i = blockIdx.x * 256 + threadIdx.x;
    if (blockIdx.x == 0) {
        int t = threadIdx.x;
        for (int j = t; j < 512; j += 256) {
            s1c[j] = f2bf(s1[j]); d1c[j] = f2bf(d1[j]); b1c[j] = f2bf(b1[j]);
        }
        if (t < OUT_C) { s2c[t] = f2bf(s2[t]); d2c[t] = f2bf(d2[t]); b2c[t] = f2bf(b2[t]); }
    }
    if (i < N_NODES) deg[i] = 1;  // self loop
}

// ---------------- GEMM1 + alpha1 fused ----------------
// h1[N,512] = x_fp32[N,256] @ W1 (bf16 MFMA); as1/ad1[n,h] from fp32 acc.
__global__ __launch_bounds__(256) void gemm1_k(const float* __restrict__ x,
                                               const unsigned short* __restrict__ Wp,
                                               const unsigned short* __restrict__ a_s,
                                               const unsigned short* __restrict__ a_d,
                                               unsigned short* __restrict__ h1,
                                               float* __restrict__ as1, float* __restrict__ ad1) {
    int w = threadIdx.x >> 6, lane = threadIdx.x & 63;
    int q = lane >> 4, l16 = lane & 15;
    int bm = blockIdx.x;
    int row = bm * 64 + w * 16 + l16;
    int rowc = row < N_NODES ? row : N_NODES - 1;
    const float* xr = x + (size_t)rowc * F_INK;
    // load full A row-strip once: 8 K-steps of 8 bf16 each (32 VGPRs)
    short8 a[8];
#pragma unroll
    for (int s = 0; s < 8; s++) {
        const float4* fp = reinterpret_cast<const float4*>(xr + s * 32 + q * 8);
        float4 f0 = fp[0], f1 = fp[1];
        short8 av;
        av[0] = (short)f2bf(f0.x); av[1] = (short)f2bf(f0.y);
        av[2] = (short)f2bf(f0.z); av[3] = (short)f2bf(f0.w);
        av[4] = (short)f2bf(f1.x); av[5] = (short)f2bf(f1.y);
        av[6] = (short)f2bf(f1.z); av[7] = (short)f2bf(f1.w);
        a[s] = av;
    }
    int orow = bm * 64 + w * 16 + q * 4;
#pragma unroll
    for (int bn = 0; bn < 8; bn++) {           // 8 column tiles = 8 heads
        f32x4 acc[4];
#pragma unroll
        for (int t = 0; t < 4; t++) acc[t] = (f32x4){0.f, 0.f, 0.f, 0.f};
#pragma unroll
        for (int s = 0; s < 8; s++) {
#pragma unroll
            for (int t = 0; t < 4; t++) {
                int col = bn * 64 + t * 16 + l16;
                short8 b = *reinterpret_cast<const short8*>(Wp + ((((s << 2) + q) * HC + col) << 3));
                acc[t] = __builtin_amdgcn_mfma_f32_16x16x32_bf16(a[s], b, acc[t], 0, 0, 0);
            }
        }
        // epilogue: store h1 tile + per-head alpha partial dots
        float sa0 = 0.f, sa1 = 0.f, sa2 = 0.f, sa3 = 0.f;
        float da0 = 0.f, da1 = 0.f, da2 = 0.f, da3 = 0.f;
#pragma unroll
        for (int t = 0; t < 4; t++) {
            int col = bn * 64 + t * 16 + l16;
            float asc = bf2f(a_s[col]);
            float adc = bf2f(a_d[col]);
            float v0 = acc[t][0], v1 = acc[t][1], v2 = acc[t][2], v3 = acc[t][3];
            sa0 += v0 * asc; da0 += v0 * adc;
            sa1 += v1 * asc; da1 += v1 * adc;
            sa2 += v2 * asc; da2 += v2 * adc;
            sa3 += v3 * asc; da3 += v3 * adc;
            if (orow + 3 < N_NODES) {
                h1[(size_t)(orow + 0) * HC + col] = f2bf(v0);
                h1[(size_t)(orow + 1) * HC + col] = f2bf(v1);
                h1[(size_t)(orow + 2) * HC + col] = f2bf(v2);
                h1[(size_t)(orow + 3) * HC + col] = f2bf(v3);
            } else {
                if (orow + 0 < N_NODES) h1[(size_t)(orow + 0) * HC + col] = f2bf(v0);
                if (orow + 1 < N_NODES) h1[(size_t)(orow + 1) * HC + col] = f2bf(v1);
                if (orow + 2 < N_NODES) h1[(size_t)(orow + 2) * HC + col] = f2bf(v2);
                if (orow + 3 < N_NODES) h1[(size_t)(orow + 3) * HC + col] = f2bf(v3);
            }
        }
        // reduce partials across the 16 lanes sharing q (xor masks touch bits 0-3 only)
#pragma unroll
        for (int m = 1; m < 16; m <<= 1) {
            sa0 += __shfl_xor(sa0, m, 64); sa1 += __shfl_xor(sa1, m, 64);
            sa2 += __shfl_xor(sa2, m, 64); sa3 += __shfl_xor(sa3, m, 64);
            da0 += __shfl_xor(da0, m, 64); da1 += __shfl_xor(da1, m, 64);
            da2 += __shfl_xor(da2, m, 64); da3 += __shfl_xor(da3, m, 64);
        }
        if (l16 < 4) {
            int rr = orow + l16;
            float sav = (l16 == 0) ? sa0 : (l16 == 1) ? sa1 : (l16 == 2) ? sa2 : sa3;
            float dav = (l16 == 0) ? da0 : (l16 == 1) ? da1 : (l16 == 2) ? da2 : da3;
            if (rr < N_NODES) { as1[rr * 8 + bn] = sav; ad1[rr * 8 + bn] = dav; }
        }
    }
}

// ---------------- GEMM2 + alpha2 fused: h2 bf16 [N,40] ----------------
__global__ __launch_bounds__(256) void gemm2_k(const unsigned short* __restrict__ a_in,
                                               const unsigned short* __restrict__ Wp,
                                               const unsigned short* __restrict__ a_s2,
                                               const unsigned short* __restrict__ a_d2,
                                               unsigned short* __restrict__ h2,
                                               float* __restrict__ as2, float* __restrict__ ad2) {
    int w = threadIdx.x >> 6, lane = threadIdx.x & 63;
    int q = lane >> 4, l16 = lane & 15;
    int bm = blockIdx.x;
    int row = bm * 64 + w * 16 + l16;
    int rowc = row < N_NODES ? row : N_NODES - 1;
    const unsigned short* ar = a_in + (size_t)rowc * HC;
    f32x4 acc[3];
#pragma unroll
    for (int t = 0; t < 3; t++) acc[t] = (f32x4){0.f, 0.f, 0.f, 0.f};
#pragma unroll
    for (int s = 0; s < HC / 32; s++) {
        short8 a = *reinterpret_cast<const short8*>(ar + s * 32 + q * 8);
#pragma unroll
        for (int t = 0; t < 3; t++) {
            int col = t * 16 + l16;
            short8 b = *reinterpret_cast<const short8*>(Wp + ((((s << 2) + q) * OUT_P + col) << 3));
            acc[t] = __builtin_amdgcn_mfma_f32_16x16x32_bf16(a, b, acc[t], 0, 0, 0);
        }
    }
    int orow = bm * 64 + w * 16 + q * 4;
    float sa0 = 0.f, sa1 = 0.f, sa2 = 0.f, sa3 = 0.f;
    float da0 = 0.f, da1 = 0.f, da2 = 0.f, da3 = 0.f;
#pragma unroll
    for (int t = 0; t < 3; t++) {
        int col = t * 16 + l16;
        if (col < OUT_C) {
            float asc = bf2f(a_s2[col]);
            float adc = bf2f(a_d2[col]);
            float v0 = acc[t][0], v1 = acc[t][1], v2 = acc[t][2], v3 = acc[t][3];
            sa0 += v0 * asc; da0 += v0 * adc;
            sa1 += v1 * asc; da1 += v1 * adc;
            sa2 += v2 * asc; da2 += v2 * adc;
            sa3 += v3 * asc; da3 += v3 * adc;
#pragma unroll
            for (int r = 0; r < 4; r++) {
                int rr = orow + r;
                if (rr < N_NODES) h2[(size_t)rr * OUT_C + col] = f2bf(acc[t][r]);
            }
        }
    }
#pragma unroll
    for (int m = 1; m < 16; m <<= 1) {
        sa0 += __shfl_xor(sa0, m, 64); sa1 += __shfl_xor(sa1, m, 64);
        sa2 += __shfl_xor(sa2, m, 64); sa3 += __shfl_xor(sa3, m, 64);
        da0 += __shfl_xor(da0, m, 64); da1 += __shfl_xor(da1, m, 64);
        da2 += __shfl_xor(da2, m, 64); da3 += __shfl_xor(da3, m, 64);
    }
    if (l16 < 4) {
        int rr = orow + l16;
        float sav = (l16 == 0) ? sa0 : (l16 == 1) ? sa1 : (l16 == 2) ? sa2 : sa3;
        float dav = (l16 == 0) ? da0 : (l16 == 1) ? da1 : (l16 == 2) ? da2 : da3;
        if (rr < N_NODES) { as2[rr] = sav; ad2[rr] = dav; }
    }
}

// ---------------- CSR build ----------------
__global__ void deg_count(const int* __restrict__ ei, int* __restrict__ deg) {
    int e = blockIdx.x * 256 + threadIdx.x;
    if (e >= N_EDGES) return;
    bool is64 = ei_is64(ei);
    int dst = is64 ? ei[2 * N_EDGES + 2 * e] : ei[N_EDGES + e];
    atomicAdd(&deg[dst], 1);
}
__global__ void scan_block(const int* __restrict__ deg, int* __restrict__ off, int* __restrict__ bsum) {
    __shared__ int s[256];
    int i = blockIdx.x * 256 + threadIdx.x;
    int v = (i < N_NODES) ? deg[i] : 0;
    s[threadIdx.x] = v;
    __syncthreads();
    for (int d = 1; d < 256; d <<= 1) {
        int t = (threadIdx.x >= d) ? s[threadIdx.x - d] : 0;
        __syncthreads();
        s[threadIdx.x] += t;
        __syncthreads();
    }
    if (i < N_NODES) off[i] = s[threadIdx.x] - v;
    if (threadIdx.x == 255) bsum[blockIdx.x] = s[255];
}
__global__ void scan_sums(const int* __restrict__ bsum, int* __restrict__ bscan, int* __restrict__ off, int nb) {
    __shared__ int s[256];
    int v = (threadIdx.x < nb) ? bsum[threadIdx.x] : 0;
    s[threadIdx.x] = v;
    __syncthreads();
    for (int d = 1; d < 256; d <<= 1) {
        int t = (threadIdx.x >= d) ? s[threadIdx.x - d] : 0;
        __syncthreads();
        s[threadIdx.x] += t;
        __syncthreads();
    }
    if (threadIdx.x < nb) bscan[threadIdx.x] = s[threadIdx.x] - v;
    if (threadIdx.x == 255) off[N_NODES] = s[255];
}
// scan finalize + self-loop scatter (no atomic needed: slot 0 of each segment)
__global__ void scan_add(int* __restrict__ off, const int* __restrict__ bscan,
                         int* __restrict__ cursor, int* __restrict__ srcs) {
    int i = blockIdx.x * 256 + threadIdx.x;
    if (i < N_NODES) {
        int v = off[i] + bscan[blockIdx.x];
        off[i] = v;
        srcs[v] = i;
        cursor[i] = v + 1;
    }
}
__global__ void scatter_edge(const int* __restrict__ ei, int* __restrict__ cursor, int* __restrict__ srcs) {
    int e = blockIdx.x * 256 + threadIdx.x;
    if (e >= N_EDGES) return;
    bool is64 = ei_is64(ei);
    int src = is64 ? ei[2 * e] : ei[e];
    int dst = is64 ? ei[2 * N_EDGES + 2 * e] : ei[N_EDGES + e];
    int pos = atomicAdd(&cursor[dst], 1);
    srcs[pos] = src;
}

// ---------------- layer-1 aggregation: one wave per dst, 4-deep pipelined ----------------
#define ACC8(u, wgt)                                                     \
    acc0 += (wgt) * bflo((u).x); acc1 += (wgt) * bfhi((u).x);            \
    acc2 += (wgt) * bflo((u).y); acc3 += (wgt) * bfhi((u).y);            \
    acc4 += (wgt) * bflo((u).z); acc5 += (wgt) * bfhi((u).z);            \
    acc6 += (wgt) * bflo((u).w); acc7 += (wgt) * bfhi((u).w);

__global__ __launch_bounds__(256) void agg1_k(const unsigned short* __restrict__ h1,
                                              const float* __restrict__ as1,
                                              const float* __restrict__ ad1,
                                              const int* __restrict__ off,
                                              const int* __restrict__ srcs,
                                              const unsigned short* __restrict__ b1,
                                              unsigned short* __restrict__ out1) {
    int wid = blockIdx.x * 4 + (threadIdx.x >> 6);
    if (wid >= N_NODES) return;
    int lane = threadIdx.x & 63;
    int h = lane >> 3;
    float adv = ad1[wid * 8 + h];
    float acc0 = 0.f, acc1 = 0.f, acc2 = 0.f, acc3 = 0.f;
    float acc4 = 0.f, acc5 = 0.f, acc6 = 0.f, acc7 = 0.f;
    float sumw = 0.f;
    int e = off[wid], e1 = off[wid + 1];
    // 4-deep: batch index loads, 4 independent row-gathers in flight
    for (; e + 4 <= e1; e += 4) {
        int s0 = srcs[e], s1 = srcs[e + 1], s2 = srcs[e + 2], s3 = srcs[e + 3];
        float A0 = as1[s0 * 8 + h], A1 = as1[s1 * 8 + h];
        float A2 = as1[s2 * 8 + h], A3 = as1[s3 * 8 + h];
        uint4 u0 = *(reinterpret_cast<const uint4*>(h1 + (size_t)s0 * HC) + lane);
        uint4 u1 = *(reinterpret_cast<const uint4*>(h1 + (size_t)s1 * HC) + lane);
        uint4 u2 = *(reinterpret_cast<const uint4*>(h1 + (size_t)s2 * HC) + lane);
        uint4 u3 = *(reinterpret_cast<const uint4*>(h1 + (size_t)s3 * HC) + lane);
        float w0 = __expf(lrelu(A0 + adv));
        float w1 = __expf(lrelu(A1 + adv));
        float w2 = __expf(lrelu(A2 + adv));
        float w3 = __expf(lrelu(A3 + adv));
        sumw += (w0 + w1) + (w2 + w3);
        ACC8(u0, w0) ACC8(u1, w1) ACC8(u2, w2) ACC8(u3, w3)
    }
    for (; e < e1; e++) {
        int s0 = srcs[e];
        float A0 = as1[s0 * 8 + h];
        uint4 u0 = *(reinterpret_cast<const uint4*>(h1 + (size_t)s0 * HC) + lane);
        float w0 = __expf(lrelu(A0 + adv));
        sumw += w0;
        ACC8(u0, w0)
    }
    float inv = 1.f / sumw;
    uint4 ub = *(reinterpret_cast<const uint4*>(b1) + lane);
    float o0 = fmaxf(acc0 * inv + bflo(ub.x), 0.f);
    float o1 = fmaxf(acc1 * inv + bfhi(ub.x), 0.f);
    float o2 = fmaxf(acc2 * inv + bflo(ub.y), 0.f);
    float o3 = fmaxf(acc3 * inv + bfhi(ub.y), 0.f);
    float o4 = fmaxf(acc4 * inv + bflo(ub.z), 0.f);
    float o5 = fmaxf(acc5 * inv + bfhi(ub.z), 0.f);
    float o6 = fmaxf(acc6 * inv + bflo(ub.w), 0.f);
    float o7 = fmaxf(acc7 * inv + bfhi(ub.w), 0.f);
    uint4 r;
    r.x = (unsigned int)f2bf(o0) | ((unsigned int)f2bf(o1) << 16);
    r.y = (unsigned int)f2bf(o2) | ((unsigned int)f2bf(o3) << 16);
    r.z = (unsigned int)f2bf(o4) | ((unsigned int)f2bf(o5) << 16);
    r.w = (unsigned int)f2bf(o6) | ((unsigned int)f2bf(o7) << 16);
    *(reinterpret_cast<uint4*>(out1 + (size_t)wid * HC) + lane) = r;
}

// ---------------- layer-2 aggregation + log_softmax (bf16 h2 gather, fp32 out) ----------
__global__ __launch_bounds__(256) void agg2_k(const unsigned short* __restrict__ h2,
                                              const float* __restrict__ as2,
                                              const float* __restrict__ ad2,
                                              const int* __restrict__ off,
                                              const int* __restrict__ srcs,
                                              const unsigned short* __restrict__ b2,
                                              float* __restrict__ outp) {
    int wid = blockIdx.x * 4 + (threadIdx.x >> 6);
    if (wid >= N_NODES) return;
    int lane = threadIdx.x & 63;
    bool act = lane < OUT_C;
    int lclamp = act ? lane : 0;
    float adv = ad2[wid];
    float acc = 0.f, sumw = 0.f;
    int e = off[wid], e1 = off[wid + 1];
    for (; e + 4 <= e1; e += 4) {
        int s0 = srcs[e], s1 = srcs[e + 1], s2 = srcs[e + 2], s3 = srcs[e + 3];
        float A0 = as2[s0], A1 = as2[s1], A2 = as2[s2], A3 = as2[s3];
        float v0 = bf2f(h2[(size_t)s0 * OUT_C + lclamp]);
        float v1 = bf2f(h2[(size_t)s1 * OUT_C + lclamp]);
        float v2 = bf2f(h2[(size_t)s2 * OUT_C + lclamp]);
        float v3 = bf2f(h2[(size_t)s3 * OUT_C + lclamp]);
        float w0 = __expf(lrelu(A0 + adv));
        float w1 = __expf(lrelu(A1 + adv));
        float w2 = __expf(lrelu(A2 + adv));
        float w3 = __expf(lrelu(A3 + adv));
        sumw += (w0 + w1) + (w2 + w3);
        acc += w0 * v0 + w1 * v1 + w2 * v2 + w3 * v3;
    }
    for (; e < e1; e++) {
        int s0 = srcs[e];
        float w0 = __expf(lrelu(as2[s0] + adv));
        sumw += w0;
        acc += w0 * bf2f(h2[(size_t)s0 * OUT_C + lclamp]);
    }
    float o = acc / sumw + bf2f(b2[lclamp]);
    float mval = act ? o : -1e30f;
#pragma unroll
    for (int m = 32; m >= 1; m >>= 1) mval = fmaxf(mval, __shfl_xor(mval, m, 64));
    float ex = act ? __expf(o - mval) : 0.f;
#pragma unroll
    for (int m = 32; m >= 1; m >>= 1) ex += __shfl_xor(ex, m, 64);
    float res = o - mval - __logf(ex);
    if (act) outp[(size_t)wid * OUT_C + lane] = res;
}

extern "C" void kernel_launch(void* const* d_in, const int* in_sizes, int n_in,
                              void* d_out, int out_size, void* d_ws, size_t ws_size,
                              hipStream_t stream) {
    const float* x      = (const float*)d_in[0];
    const int*   ei     = (const int*)d_in[1];
    const float* W1     = (const float*)d_in[2];
    const float* as1raw = (const float*)d_in[3];
    const float* ad1raw = (const float*)d_in[4];
    const float* b1raw  = (const float*)d_in[5];
    const float* W2     = (const float*)d_in[6];
    const float* as2raw = (const float*)d_in[7];
    const float* ad2raw = (const float*)d_in[8];
    const float* b2raw  = (const float*)d_in[9];
    float* out = (float*)d_out;

    char* p = (char*)d_ws;
    auto alloc = [&](size_t bytes) -> char* {
        char* r = p;
        p += (bytes + 255) & ~(size_t)255;
        return r;
    };
    unsigned short* s1c  = (unsigned short*)alloc(512 * 2);
    unsigned short* d1c  = (unsigned short*)alloc(512 * 2);
    unsigned short* b1c  = (unsigned short*)alloc(512 * 2);
    unsigned short* s2c  = (unsigned short*)alloc(OUT_C * 2);
    unsigned short* d2c  = (unsigned short*)alloc(OUT_C * 2);
    unsigned short* b2c  = (unsigned short*)alloc(OUT_C * 2);
    unsigned short* h1   = (unsigned short*)alloc((size_t)N_NODES * HC * 2);   // 51.2 MB
    unsigned short* out1 = (unsigned short*)alloc((size_t)N_NODES * HC * 2);   // 51.2 MB
    unsigned short* h2   = (unsigned short*)alloc((size_t)N_NODES * OUT_C * 2);// 4 MB
    float* as1  = (float*)alloc((size_t)N_NODES * 8 * 4);
    float* ad1  = (float*)alloc((size_t)N_NODES * 8 * 4);
    float* as2  = (float*)alloc((size_t)N_NODES * 4);
    float* ad2  = (float*)alloc((size_t)N_NODES * 4);
    int* deg    = (int*)alloc((size_t)N_NODES * 4);
    int* off    = (int*)alloc((size_t)(N_NODES + 1) * 4);
    int* cursor = (int*)alloc((size_t)N_NODES * 4);
    int* srcs   = (int*)alloc((size_t)(N_EDGES + N_NODES) * 4);
    unsigned short* W1p = (unsigned short*)alloc((size_t)F_INK * HC * 2);
    unsigned short* W2p = (unsigned short*)alloc((size_t)HC * OUT_P * 2);
    int* bsum  = (int*)alloc(256 * 4);
    int* bscan = (int*)alloc(256 * 4);
    (void)ws_size; (void)in_sizes; (void)n_in; (void)out_size;

    const int NB = (N_NODES + 255) / 256;  // 196

    pack_w1<<<(F_INK * HC + 255) / 256, 256, 0, stream>>>(W1, W1p);
    pack_w2<<<(HC * OUT_P + 255) / 256, 256, 0, stream>>>(W2, W2p);
    canon_small<<<NB, 256, 0, stream>>>(as1raw, ad1raw, b1raw, as2raw, ad2raw, b2raw,
                                        s1c, d1c, b1c, s2c, d2c, b2c, deg);
    deg_count<<<(N_EDGES + 255) / 256, 256, 0, stream>>>(ei, deg);
    scan_block<<<NB, 256, 0, stream>>>(deg, off, bsum);
    scan_sums<<<1, 256, 0, stream>>>(bsum, bscan, off, NB);
    scan_add<<<NB, 256, 0, stream>>>(off, bscan, cursor, srcs);
    scatter_edge<<<(N_EDGES + 255) / 256, 256, 0, stream>>>(ei, cursor, srcs);
    gemm1_k<<<(N_NODES + 63) / 64, 256, 0, stream>>>(x, W1p, s1c, d1c, h1, as1, ad1);
    agg1_k<<<(N_NODES + 3) / 4, 256, 0, stream>>>(h1, as1, ad1, off, srcs, b1c, out1);
    gemm2_k<<<(N_NODES + 63) / 64, 256, 0, stream>>>(out1, W2p, s2c, d2c, h2, as2, ad2);
    agg2_k<<<(N_NODES + 3) / 4, 256, 0, stream>>>(h2, as2, ad2, off, srcs, b2c, out);
}

// Round 5
// 395.804 us; speedup vs baseline: 1.4375x; 1.0985x over previous
//
#include <hip/hip_runtime.h>

#define N_NODES 50000
#define N_EDGES 800000
#define F_INK   256
#define HC      512   // H*C = 8*64
#define OUT_C   40
#define OUT_P   48    // padded cols for GEMM2
#define NEG     0.2f

typedef short short8 __attribute__((ext_vector_type(8)));
typedef float f32x4 __attribute__((ext_vector_type(4)));
typedef float f32x2 __attribute__((ext_vector_type(2)));

__device__ __forceinline__ float bf2f(unsigned short u) {
    union { unsigned int i; float f; } v; v.i = ((unsigned int)u) << 16; return v.f;
}
__device__ __forceinline__ unsigned short f2bf(float f) {
    union { float f; unsigned int i; } v; v.f = f;
    unsigned int x = v.i;
    return (unsigned short)((x + 0x7fffu + ((x >> 16) & 1u)) >> 16);
}
__device__ __forceinline__ float bflo(unsigned int u) {
    union { unsigned int i; float f; } v; v.i = u << 16; return v.f;
}
__device__ __forceinline__ float bfhi(unsigned int u) {
    union { unsigned int i; float f; } v; v.i = u & 0xffff0000u; return v.f;
}
// int64-vs-int32 edge_index probe: for int64 the high words of src[0..2] are 0.
__device__ __forceinline__ bool ei_is64(const int* ei) {
    return ei[1] == 0 && ei[3] == 0 && ei[5] == 0;
}
__device__ __forceinline__ float lrelu(float x) { return x > 0.f ? x : NEG * x; }

// ---------------- weight packing (fp32 in, packed bf16 out) ----------------
// B-frag layout (16x16x32): lane l (q=l>>4, n=l&15) holds B[k=q*8+j][n], j=0..7.
// Wp[((s*4+q)*LD + n)*8 + j] = W[k][n], k=s*32+q*8+j.
__global__ void pack_w1(const float* __restrict__ W, unsigned short* __restrict__ Wp) {
    int t = blockIdx.x * 256 + threadIdx.x;
    if (t >= F_INK * HC) return;
    int k = t / HC, n = t % HC;
    int s = k >> 5, q = (k >> 3) & 3, j = k & 7;
    Wp[((((s << 2) + q) * HC + n) << 3) + j] = f2bf(W[k * HC + n]);
}
__global__ void pack_w2(const float* __restrict__ W, unsigned short* __restrict__ Wp) {
    int t = blockIdx.x * 256 + threadIdx.x;
    if (t >= HC * OUT_P) return;
    int k = t / OUT_P, n = t % OUT_P;
    int s = k >> 5, q = (k >> 3) & 3, j = k & 7;
    unsigned short v = (n < OUT_C) ? f2bf(W[k * OUT_C + n]) : (unsigned short)0;
    Wp[((((s << 2) + q) * OUT_P + n) << 3) + j] = v;
}

// ---------------- canon small fp32 arrays -> bf16, + deg init ----------------
__global__ void canon_small(const float* __restrict__ s1, const float* __restrict__ d1,
                            const float* __restrict__ b1, const float* __restrict__ s2,
                            const float* __restrict__ d2, const float* __restrict__ b2,
                            unsigned short* __restrict__ s1c, unsigned short* __restrict__ d1c,
                            unsigned short* __restrict__ b1c, unsigned short* __restrict__ s2c,
                            unsigned short* __restrict__ d2c, unsigned short* __restrict__ b2c,
                            int* __restrict__ deg) {
    int i = blockIdx.x * 256 + threadIdx.x;
    if (blockIdx.x == 0) {
        int t = threadIdx.x;
        for (int j = t; j < 512; j += 256) {
            s1c[j] = f2bf(s1[j]); d1c[j] = f2bf(d1[j]); b1c[j] = f2bf(b1[j]);
        }
        if (t < OUT_C) { s2c[t] = f2bf(s2[t]); d2c[t] = f2bf(d2[t]); b2c[t] = f2bf(b2[t]); }
    }
    if (i < N_NODES) deg[i] = 1;  // self loop
}

// ---------------- GEMM1 + alpha1 fused ----------------
// h1[N,512] = x_fp32[N,256] @ W1 (bf16 MFMA); as1/ad1[n,h] from fp32 acc.
__global__ __launch_bounds__(256) void gemm1_k(const float* __restrict__ x,
                                               const unsigned short* __restrict__ Wp,
                                               const unsigned short* __restrict__ a_s,
                                               const unsigned short* __restrict__ a_d,
                                               unsigned short* __restrict__ h1,
                                               float* __restrict__ as1, float* __restrict__ ad1) {
    int w = threadIdx.x >> 6, lane = threadIdx.x & 63;
    int q = lane >> 4, l16 = lane & 15;
    int bm = blockIdx.x;
    int row = bm * 64 + w * 16 + l16;
    int rowc = row < N_NODES ? row : N_NODES - 1;
    const float* xr = x + (size_t)rowc * F_INK;
    // load full A row-strip once: 8 K-steps of 8 bf16 each (32 VGPRs)
    short8 a[8];
#pragma unroll
    for (int s = 0; s < 8; s++) {
        const float4* fp = reinterpret_cast<const float4*>(xr + s * 32 + q * 8);
        float4 f0 = fp[0], f1 = fp[1];
        short8 av;
        av[0] = (short)f2bf(f0.x); av[1] = (short)f2bf(f0.y);
        av[2] = (short)f2bf(f0.z); av[3] = (short)f2bf(f0.w);
        av[4] = (short)f2bf(f1.x); av[5] = (short)f2bf(f1.y);
        av[6] = (short)f2bf(f1.z); av[7] = (short)f2bf(f1.w);
        a[s] = av;
    }
    int orow = bm * 64 + w * 16 + q * 4;
#pragma unroll
    for (int bn = 0; bn < 8; bn++) {           // 8 column tiles = 8 heads
        f32x4 acc[4];
#pragma unroll
        for (int t = 0; t < 4; t++) acc[t] = (f32x4){0.f, 0.f, 0.f, 0.f};
#pragma unroll
        for (int s = 0; s < 8; s++) {
#pragma unroll
            for (int t = 0; t < 4; t++) {
                int col = bn * 64 + t * 16 + l16;
                short8 b = *reinterpret_cast<const short8*>(Wp + ((((s << 2) + q) * HC + col) << 3));
                acc[t] = __builtin_amdgcn_mfma_f32_16x16x32_bf16(a[s], b, acc[t], 0, 0, 0);
            }
        }
        // epilogue: store h1 tile + per-head alpha partial dots
        float sa0 = 0.f, sa1 = 0.f, sa2 = 0.f, sa3 = 0.f;
        float da0 = 0.f, da1 = 0.f, da2 = 0.f, da3 = 0.f;
#pragma unroll
        for (int t = 0; t < 4; t++) {
            int col = bn * 64 + t * 16 + l16;
            float asc = bf2f(a_s[col]);
            float adc = bf2f(a_d[col]);
            float v0 = acc[t][0], v1 = acc[t][1], v2 = acc[t][2], v3 = acc[t][3];
            sa0 += v0 * asc; da0 += v0 * adc;
            sa1 += v1 * asc; da1 += v1 * adc;
            sa2 += v2 * asc; da2 += v2 * adc;
            sa3 += v3 * asc; da3 += v3 * adc;
            if (orow + 3 < N_NODES) {
                h1[(size_t)(orow + 0) * HC + col] = f2bf(v0);
                h1[(size_t)(orow + 1) * HC + col] = f2bf(v1);
                h1[(size_t)(orow + 2) * HC + col] = f2bf(v2);
                h1[(size_t)(orow + 3) * HC + col] = f2bf(v3);
            } else {
                if (orow + 0 < N_NODES) h1[(size_t)(orow + 0) * HC + col] = f2bf(v0);
                if (orow + 1 < N_NODES) h1[(size_t)(orow + 1) * HC + col] = f2bf(v1);
                if (orow + 2 < N_NODES) h1[(size_t)(orow + 2) * HC + col] = f2bf(v2);
                if (orow + 3 < N_NODES) h1[(size_t)(orow + 3) * HC + col] = f2bf(v3);
            }
        }
        // reduce partials across the 16 lanes sharing q (xor masks touch bits 0-3 only)
#pragma unroll
        for (int m = 1; m < 16; m <<= 1) {
            sa0 += __shfl_xor(sa0, m, 64); sa1 += __shfl_xor(sa1, m, 64);
            sa2 += __shfl_xor(sa2, m, 64); sa3 += __shfl_xor(sa3, m, 64);
            da0 += __shfl_xor(da0, m, 64); da1 += __shfl_xor(da1, m, 64);
            da2 += __shfl_xor(da2, m, 64); da3 += __shfl_xor(da3, m, 64);
        }
        if (l16 < 4) {
            int rr = orow + l16;
            float sav = (l16 == 0) ? sa0 : (l16 == 1) ? sa1 : (l16 == 2) ? sa2 : sa3;
            float dav = (l16 == 0) ? da0 : (l16 == 1) ? da1 : (l16 == 2) ? da2 : da3;
            if (rr < N_NODES) { as1[rr * 8 + bn] = sav; ad1[rr * 8 + bn] = dav; }
        }
    }
}

// ---------------- h1 bf16 -> fp8 e4m3 (message payload for the gather) ----------------
__global__ __launch_bounds__(256) void h1_to_fp8(const unsigned short* __restrict__ h1,
                                                 uint2* __restrict__ h1f8, int n8) {
    int i = blockIdx.x * 256 + threadIdx.x;   // units of 8 elements
    if (i >= n8) return;
    uint4 u = reinterpret_cast<const uint4*>(h1)[i];
    int w0 = __builtin_amdgcn_cvt_pk_fp8_f32(bflo(u.x), bfhi(u.x), 0, false);
    w0     = __builtin_amdgcn_cvt_pk_fp8_f32(bflo(u.y), bfhi(u.y), w0, true);
    int w1 = __builtin_amdgcn_cvt_pk_fp8_f32(bflo(u.z), bfhi(u.z), 0, false);
    w1     = __builtin_amdgcn_cvt_pk_fp8_f32(bflo(u.w), bfhi(u.w), w1, true);
    h1f8[i] = make_uint2((unsigned)w0, (unsigned)w1);
}

// ---------------- GEMM2 + alpha2 fused: h2 bf16 [N,40] ----------------
__global__ __launch_bounds__(256) void gemm2_k(const unsigned short* __restrict__ a_in,
                                               const unsigned short* __restrict__ Wp,
                                               const unsigned short* __restrict__ a_s2,
                                               const unsigned short* __restrict__ a_d2,
                                               unsigned short* __restrict__ h2,
                                               float* __restrict__ as2, float* __restrict__ ad2) {
    int w = threadIdx.x >> 6, lane = threadIdx.x & 63;
    int q = lane >> 4, l16 = lane & 15;
    int bm = blockIdx.x;
    int row = bm * 64 + w * 16 + l16;
    int rowc = row < N_NODES ? row : N_NODES - 1;
    const unsigned short* ar = a_in + (size_t)rowc * HC;
    f32x4 acc[3];
#pragma unroll
    for (int t = 0; t < 3; t++) acc[t] = (f32x4){0.f, 0.f, 0.f, 0.f};
#pragma unroll
    for (int s = 0; s < HC / 32; s++) {
        short8 a = *reinterpret_cast<const short8*>(ar + s * 32 + q * 8);
#pragma unroll
        for (int t = 0; t < 3; t++) {
            int col = t * 16 + l16;
            short8 b = *reinterpret_cast<const short8*>(Wp + ((((s << 2) + q) * OUT_P + col) << 3));
            acc[t] = __builtin_amdgcn_mfma_f32_16x16x32_bf16(a, b, acc[t], 0, 0, 0);
        }
    }
    int orow = bm * 64 + w * 16 + q * 4;
    float sa0 = 0.f, sa1 = 0.f, sa2 = 0.f, sa3 = 0.f;
    float da0 = 0.f, da1 = 0.f, da2 = 0.f, da3 = 0.f;
#pragma unroll
    for (int t = 0; t < 3; t++) {
        int col = t * 16 + l16;
        if (col < OUT_C) {
            float asc = bf2f(a_s2[col]);
            float adc = bf2f(a_d2[col]);
            float v0 = acc[t][0], v1 = acc[t][1], v2 = acc[t][2], v3 = acc[t][3];
            sa0 += v0 * asc; da0 += v0 * adc;
            sa1 += v1 * asc; da1 += v1 * adc;
            sa2 += v2 * asc; da2 += v2 * adc;
            sa3 += v3 * asc; da3 += v3 * adc;
#pragma unroll
            for (int r = 0; r < 4; r++) {
                int rr = orow + r;
                if (rr < N_NODES) h2[(size_t)rr * OUT_C + col] = f2bf(acc[t][r]);
            }
        }
    }
#pragma unroll
    for (int m = 1; m < 16; m <<= 1) {
        sa0 += __shfl_xor(sa0, m, 64); sa1 += __shfl_xor(sa1, m, 64);
        sa2 += __shfl_xor(sa2, m, 64); sa3 += __shfl_xor(sa3, m, 64);
        da0 += __shfl_xor(da0, m, 64); da1 += __shfl_xor(da1, m, 64);
        da2 += __shfl_xor(da2, m, 64); da3 += __shfl_xor(da3, m, 64);
    }
    if (l16 < 4) {
        int rr = orow + l16;
        float sav = (l16 == 0) ? sa0 : (l16 == 1) ? sa1 : (l16 == 2) ? sa2 : sa3;
        float dav = (l16 == 0) ? da0 : (l16 == 1) ? da1 : (l16 == 2) ? da2 : da3;
        if (rr < N_NODES) { as2[rr] = sav; ad2[rr] = dav; }
    }
}

// ---------------- CSR build ----------------
__global__ void deg_count(const int* __restrict__ ei, int* __restrict__ deg) {
    int e = blockIdx.x * 256 + threadIdx.x;
    if (e >= N_EDGES) return;
    bool is64 = ei_is64(ei);
    int dst = is64 ? ei[2 * N_EDGES + 2 * e] : ei[N_EDGES + e];
    atomicAdd(&deg[dst], 1);
}
__global__ void scan_block(const int* __restrict__ deg, int* __restrict__ off, int* __restrict__ bsum) {
    __shared__ int s[256];
    int i = blockIdx.x * 256 + threadIdx.x;
    int v = (i < N_NODES) ? deg[i] : 0;
    s[threadIdx.x] = v;
    __syncthreads();
    for (int d = 1; d < 256; d <<= 1) {
        int t = (threadIdx.x >= d) ? s[threadIdx.x - d] : 0;
        __syncthreads();
        s[threadIdx.x] += t;
        __syncthreads();
    }
    if (i < N_NODES) off[i] = s[threadIdx.x] - v;
    if (threadIdx.x == 255) bsum[blockIdx.x] = s[255];
}
__global__ void scan_sums(const int* __restrict__ bsum, int* __restrict__ bscan, int* __restrict__ off, int nb) {
    __shared__ int s[256];
    int v = (threadIdx.x < nb) ? bsum[threadIdx.x] : 0;
    s[threadIdx.x] = v;
    __syncthreads();
    for (int d = 1; d < 256; d <<= 1) {
        int t = (threadIdx.x >= d) ? s[threadIdx.x - d] : 0;
        __syncthreads();
        s[threadIdx.x] += t;
        __syncthreads();
    }
    if (threadIdx.x < nb) bscan[threadIdx.x] = s[threadIdx.x] - v;
    if (threadIdx.x == 255) off[N_NODES] = s[255];
}
// scan finalize + self-loop scatter (no atomic needed: slot 0 of each segment)
__global__ void scan_add(int* __restrict__ off, const int* __restrict__ bscan,
                         int* __restrict__ cursor, int* __restrict__ srcs) {
    int i = blockIdx.x * 256 + threadIdx.x;
    if (i < N_NODES) {
        int v = off[i] + bscan[blockIdx.x];
        off[i] = v;
        srcs[v] = i;
        cursor[i] = v + 1;
    }
}
__global__ void scatter_edge(const int* __restrict__ ei, int* __restrict__ cursor, int* __restrict__ srcs) {
    int e = blockIdx.x * 256 + threadIdx.x;
    if (e >= N_EDGES) return;
    bool is64 = ei_is64(ei);
    int src = is64 ? ei[2 * e] : ei[e];
    int dst = is64 ? ei[2 * N_EDGES + 2 * e] : ei[N_EDGES + e];
    int pos = atomicAdd(&cursor[dst], 1);
    srcs[pos] = src;
}

// ---------------- layer-1 aggregation: one wave per dst, fp8 gather ----------------
// lane l owns channels [l*8, l*8+8); per edge it loads 8 fp8 bytes (uint2).
#define ACCF8(u, wgt)                                                        \
    {                                                                        \
        f32x2 p0 = __builtin_amdgcn_cvt_pk_f32_fp8((int)(u).x, false);       \
        f32x2 p1 = __builtin_amdgcn_cvt_pk_f32_fp8((int)(u).x, true);        \
        f32x2 p2 = __builtin_amdgcn_cvt_pk_f32_fp8((int)(u).y, false);       \
        f32x2 p3 = __builtin_amdgcn_cvt_pk_f32_fp8((int)(u).y, true);        \
        acc0 += (wgt) * p0[0]; acc1 += (wgt) * p0[1];                        \
        acc2 += (wgt) * p1[0]; acc3 += (wgt) * p1[1];                        \
        acc4 += (wgt) * p2[0]; acc5 += (wgt) * p2[1];                        \
        acc6 += (wgt) * p3[0]; acc7 += (wgt) * p3[1];                        \
    }

__global__ __launch_bounds__(256) void agg1_k(const unsigned char* __restrict__ h1f8,
                                              const float* __restrict__ as1,
                                              const float* __restrict__ ad1,
                                              const int* __restrict__ off,
                                              const int* __restrict__ srcs,
                                              const unsigned short* __restrict__ b1,
                                              unsigned short* __restrict__ out1) {
    int wid = blockIdx.x * 4 + (threadIdx.x >> 6);
    if (wid >= N_NODES) return;
    int lane = threadIdx.x & 63;
    int h = lane >> 3;
    float adv = ad1[wid * 8 + h];
    float acc0 = 0.f, acc1 = 0.f, acc2 = 0.f, acc3 = 0.f;
    float acc4 = 0.f, acc5 = 0.f, acc6 = 0.f, acc7 = 0.f;
    float sumw = 0.f;
    int e = off[wid], e1 = off[wid + 1];
    for (; e + 4 <= e1; e += 4) {
        int s0 = srcs[e], s1 = srcs[e + 1], s2 = srcs[e + 2], s3 = srcs[e + 3];
        float A0 = as1[s0 * 8 + h], A1 = as1[s1 * 8 + h];
        float A2 = as1[s2 * 8 + h], A3 = as1[s3 * 8 + h];
        uint2 u0 = reinterpret_cast<const uint2*>(h1f8 + (size_t)s0 * HC)[lane];
        uint2 u1 = reinterpret_cast<const uint2*>(h1f8 + (size_t)s1 * HC)[lane];
        uint2 u2 = reinterpret_cast<const uint2*>(h1f8 + (size_t)s2 * HC)[lane];
        uint2 u3 = reinterpret_cast<const uint2*>(h1f8 + (size_t)s3 * HC)[lane];
        float w0 = __expf(lrelu(A0 + adv));
        float w1 = __expf(lrelu(A1 + adv));
        float w2 = __expf(lrelu(A2 + adv));
        float w3 = __expf(lrelu(A3 + adv));
        sumw += (w0 + w1) + (w2 + w3);
        ACCF8(u0, w0) ACCF8(u1, w1) ACCF8(u2, w2) ACCF8(u3, w3)
    }
    for (; e < e1; e++) {
        int s0 = srcs[e];
        float A0 = as1[s0 * 8 + h];
        uint2 u0 = reinterpret_cast<const uint2*>(h1f8 + (size_t)s0 * HC)[lane];
        float w0 = __expf(lrelu(A0 + adv));
        sumw += w0;
        ACCF8(u0, w0)
    }
    float inv = 1.f / sumw;
    uint4 ub = *(reinterpret_cast<const uint4*>(b1) + lane);
    float o0 = fmaxf(acc0 * inv + bflo(ub.x), 0.f);
    float o1 = fmaxf(acc1 * inv + bfhi(ub.x), 0.f);
    float o2 = fmaxf(acc2 * inv + bflo(ub.y), 0.f);
    float o3 = fmaxf(acc3 * inv + bfhi(ub.y), 0.f);
    float o4 = fmaxf(acc4 * inv + bflo(ub.z), 0.f);
    float o5 = fmaxf(acc5 * inv + bfhi(ub.z), 0.f);
    float o6 = fmaxf(acc6 * inv + bflo(ub.w), 0.f);
    float o7 = fmaxf(acc7 * inv + bfhi(ub.w), 0.f);
    uint4 r;
    r.x = (unsigned int)f2bf(o0) | ((unsigned int)f2bf(o1) << 16);
    r.y = (unsigned int)f2bf(o2) | ((unsigned int)f2bf(o3) << 16);
    r.z = (unsigned int)f2bf(o4) | ((unsigned int)f2bf(o5) << 16);
    r.w = (unsigned int)f2bf(o6) | ((unsigned int)f2bf(o7) << 16);
    *(reinterpret_cast<uint4*>(out1 + (size_t)wid * HC) + lane) = r;
}

// ---------------- layer-2 aggregation + log_softmax (bf16 h2 gather, fp32 out) ----------
__global__ __launch_bounds__(256) void agg2_k(const unsigned short* __restrict__ h2,
                                              const float* __restrict__ as2,
                                              const float* __restrict__ ad2,
                                              const int* __restrict__ off,
                                              const int* __restrict__ srcs,
                                              const unsigned short* __restrict__ b2,
                                              float* __restrict__ outp) {
    int wid = blockIdx.x * 4 + (threadIdx.x >> 6);
    if (wid >= N_NODES) return;
    int lane = threadIdx.x & 63;
    bool act = lane < OUT_C;
    int lclamp = act ? lane : 0;
    float adv = ad2[wid];
    float acc = 0.f, sumw = 0.f;
    int e = off[wid], e1 = off[wid + 1];
    for (; e + 4 <= e1; e += 4) {
        int s0 = srcs[e], s1 = srcs[e + 1], s2 = srcs[e + 2], s3 = srcs[e + 3];
        float A0 = as2[s0], A1 = as2[s1], A2 = as2[s2], A3 = as2[s3];
        float v0 = bf2f(h2[(size_t)s0 * OUT_C + lclamp]);
        float v1 = bf2f(h2[(size_t)s1 * OUT_C + lclamp]);
        float v2 = bf2f(h2[(size_t)s2 * OUT_C + lclamp]);
        float v3 = bf2f(h2[(size_t)s3 * OUT_C + lclamp]);
        float w0 = __expf(lrelu(A0 + adv));
        float w1 = __expf(lrelu(A1 + adv));
        float w2 = __expf(lrelu(A2 + adv));
        float w3 = __expf(lrelu(A3 + adv));
        sumw += (w0 + w1) + (w2 + w3);
        acc += w0 * v0 + w1 * v1 + w2 * v2 + w3 * v3;
    }
    for (; e < e1; e++) {
        int s0 = srcs[e];
        float w0 = __expf(lrelu(as2[s0] + adv));
        sumw += w0;
        acc += w0 * bf2f(h2[(size_t)s0 * OUT_C + lclamp]);
    }
    float o = acc / sumw + bf2f(b2[lclamp]);
    float mval = act ? o : -1e30f;
#pragma unroll
    for (int m = 32; m >= 1; m >>= 1) mval = fmaxf(mval, __shfl_xor(mval, m, 64));
    float ex = act ? __expf(o - mval) : 0.f;
#pragma unroll
    for (int m = 32; m >= 1; m >>= 1) ex += __shfl_xor(ex, m, 64);
    float res = o - mval - __logf(ex);
    if (act) outp[(size_t)wid * OUT_C + lane] = res;
}

extern "C" void kernel_launch(void* const* d_in, const int* in_sizes, int n_in,
                              void* d_out, int out_size, void* d_ws, size_t ws_size,
                              hipStream_t stream) {
    const float* x      = (const float*)d_in[0];
    const int*   ei     = (const int*)d_in[1];
    const float* W1     = (const float*)d_in[2];
    const float* as1raw = (const float*)d_in[3];
    const float* ad1raw = (const float*)d_in[4];
    const float* b1raw  = (const float*)d_in[5];
    const float* W2     = (const float*)d_in[6];
    const float* as2raw = (const float*)d_in[7];
    const float* ad2raw = (const float*)d_in[8];
    const float* b2raw  = (const float*)d_in[9];
    float* out = (float*)d_out;

    char* p = (char*)d_ws;
    auto alloc = [&](size_t bytes) -> char* {
        char* r = p;
        p += (bytes + 255) & ~(size_t)255;
        return r;
    };
    unsigned short* s1c  = (unsigned short*)alloc(512 * 2);
    unsigned short* d1c  = (unsigned short*)alloc(512 * 2);
    unsigned short* b1c  = (unsigned short*)alloc(512 * 2);
    unsigned short* s2c  = (unsigned short*)alloc(OUT_C * 2);
    unsigned short* d2c  = (unsigned short*)alloc(OUT_C * 2);
    unsigned short* b2c  = (unsigned short*)alloc(OUT_C * 2);
    unsigned short* h1   = (unsigned short*)alloc((size_t)N_NODES * HC * 2);   // 51.2 MB
    unsigned char*  h1f8 = (unsigned char*)alloc((size_t)N_NODES * HC);        // 25.6 MB
    unsigned short* out1 = (unsigned short*)alloc((size_t)N_NODES * HC * 2);   // 51.2 MB
    unsigned short* h2   = (unsigned short*)alloc((size_t)N_NODES * OUT_C * 2);// 4 MB
    float* as1  = (float*)alloc((size_t)N_NODES * 8 * 4);
    float* ad1  = (float*)alloc((size_t)N_NODES * 8 * 4);
    float* as2  = (float*)alloc((size_t)N_NODES * 4);
    float* ad2  = (float*)alloc((size_t)N_NODES * 4);
    int* deg    = (int*)alloc((size_t)N_NODES * 4);
    int* off    = (int*)alloc((size_t)(N_NODES + 1) * 4);
    int* cursor = (int*)alloc((size_t)N_NODES * 4);
    int* srcs   = (int*)alloc((size_t)(N_EDGES + N_NODES) * 4);
    unsigned short* W1p = (unsigned short*)alloc((size_t)F_INK * HC * 2);
    unsigned short* W2p = (unsigned short*)alloc((size_t)HC * OUT_P * 2);
    int* bsum  = (int*)alloc(256 * 4);
    int* bscan = (int*)alloc(256 * 4);
    (void)ws_size; (void)in_sizes; (void)n_in; (void)out_size;

    const int NB = (N_NODES + 255) / 256;  // 196

    pack_w1<<<(F_INK * HC + 255) / 256, 256, 0, stream>>>(W1, W1p);
    pack_w2<<<(HC * OUT_P + 255) / 256, 256, 0, stream>>>(W2, W2p);
    canon_small<<<NB, 256, 0, stream>>>(as1raw, ad1raw, b1raw, as2raw, ad2raw, b2raw,
                                        s1c, d1c, b1c, s2c, d2c, b2c, deg);
    deg_count<<<(N_EDGES + 255) / 256, 256, 0, stream>>>(ei, deg);
    scan_block<<<NB, 256, 0, stream>>>(deg, off, bsum);
    scan_sums<<<1, 256, 0, stream>>>(bsum, bscan, off, NB);
    scan_add<<<NB, 256, 0, stream>>>(off, bscan, cursor, srcs);
    scatter_edge<<<(N_EDGES + 255) / 256, 256, 0, stream>>>(ei, cursor, srcs);
    gemm1_k<<<(N_NODES + 63) / 64, 256, 0, stream>>>(x, W1p, s1c, d1c, h1, as1, ad1);
    h1_to_fp8<<<(N_NODES * HC / 8 + 255) / 256, 256, 0, stream>>>(h1, (uint2*)h1f8, N_NODES * HC / 8);
    agg1_k<<<(N_NODES + 3) / 4, 256, 0, stream>>>(h1f8, as1, ad1, off, srcs, b1c, out1);
    gemm2_k<<<(N_NODES + 63) / 64, 256, 0, stream>>>(out1, W2p, s2c, d2c, h2, as2, ad2);
    agg2_k<<<(N_NODES + 3) / 4, 256, 0, stream>>>(h2, as2, ad2, off, srcs, b2c, out);
}

// Round 6
// 382.726 us; speedup vs baseline: 1.4866x; 1.0342x over previous
//
#include <hip/hip_runtime.h>

#define N_NODES 50000
#define N_EDGES 800000
#define E_TOT   (N_EDGES + N_NODES)
#define F_INK   256
#define HC      512   // H*C = 8*64
#define OUT_C   40
#define OUT_P   48    // padded cols for GEMM2
#define NEG     0.2f

typedef short short8 __attribute__((ext_vector_type(8)));
typedef float f32x4 __attribute__((ext_vector_type(4)));
typedef float f32x2 __attribute__((ext_vector_type(2)));

__device__ __forceinline__ float bf2f(unsigned short u) {
    union { unsigned int i; float f; } v; v.i = ((unsigned int)u) << 16; return v.f;
}
__device__ __forceinline__ unsigned short f2bf(float f) {
    union { float f; unsigned int i; } v; v.f = f;
    unsigned int x = v.i;
    return (unsigned short)((x + 0x7fffu + ((x >> 16) & 1u)) >> 16);
}
__device__ __forceinline__ float bflo(unsigned int u) {
    union { unsigned int i; float f; } v; v.i = u << 16; return v.f;
}
__device__ __forceinline__ float bfhi(unsigned int u) {
    union { unsigned int i; float f; } v; v.i = u & 0xffff0000u; return v.f;
}
__device__ __forceinline__ bool ei_is64(const int* ei) {
    return ei[1] == 0 && ei[3] == 0 && ei[5] == 0;
}
__device__ __forceinline__ float lrelu(float x) { return x > 0.f ? x : NEG * x; }
__device__ __forceinline__ unsigned char f2fp8(float v) {
    return (unsigned char)(__builtin_amdgcn_cvt_pk_fp8_f32(v, v, 0, false) & 0xff);
}

// ---------------- weight packing (fp32 in, packed bf16 out) ----------------
// B-frag layout (16x16x32): lane l (q=l>>4, n=l&15) holds B[k=q*8+j][n], j=0..7.
__global__ void pack_w1(const float* __restrict__ W, unsigned short* __restrict__ Wp) {
    int t = blockIdx.x * 256 + threadIdx.x;
    if (t >= F_INK * HC) return;
    int k = t / HC, n = t % HC;
    int s = k >> 5, q = (k >> 3) & 3, j = k & 7;
    Wp[((((s << 2) + q) * HC + n) << 3) + j] = f2bf(W[k * HC + n]);
}
__global__ void pack_w2(const float* __restrict__ W, unsigned short* __restrict__ Wp) {
    int t = blockIdx.x * 256 + threadIdx.x;
    if (t >= HC * OUT_P) return;
    int k = t / OUT_P, n = t % OUT_P;
    int s = k >> 5, q = (k >> 3) & 3, j = k & 7;
    unsigned short v = (n < OUT_C) ? f2bf(W[k * OUT_C + n]) : (unsigned short)0;
    Wp[((((s << 2) + q) * OUT_P + n) << 3) + j] = v;
}

// ---------------- canon small fp32 arrays -> bf16, + deg init ----------------
__global__ void canon_small(const float* __restrict__ s1, const float* __restrict__ d1,
                            const float* __restrict__ b1, const float* __restrict__ s2,
                            const float* __restrict__ d2, const float* __restrict__ b2,
                            unsigned short* __restrict__ s1c, unsigned short* __restrict__ d1c,
                            unsigned short* __restrict__ b1c, unsigned short* __restrict__ s2c,
                            unsigned short* __restrict__ d2c, unsigned short* __restrict__ b2c,
                            int* __restrict__ deg) {
    int i = blockIdx.x * 256 + threadIdx.x;
    if (blockIdx.x == 0) {
        int t = threadIdx.x;
        for (int j = t; j < 512; j += 256) {
            s1c[j] = f2bf(s1[j]); d1c[j] = f2bf(d1[j]); b1c[j] = f2bf(b1[j]);
        }
        if (t < OUT_C) { s2c[t] = f2bf(s2[t]); d2c[t] = f2bf(d2[t]); b2c[t] = f2bf(b2[t]); }
    }
    if (i < N_NODES) deg[i] = 1;  // self loop
}

// ---------------- GEMM1 + alpha1 fused; writes h1 as fp8 directly ----------------
__global__ __launch_bounds__(256) void gemm1_k(const float* __restrict__ x,
                                               const unsigned short* __restrict__ Wp,
                                               const unsigned short* __restrict__ a_s,
                                               const unsigned short* __restrict__ a_d,
                                               unsigned char* __restrict__ h1f8,
                                               float* __restrict__ as1, float* __restrict__ ad1) {
    int w = threadIdx.x >> 6, lane = threadIdx.x & 63;
    int q = lane >> 4, l16 = lane & 15;
    int bm = blockIdx.x;
    int row = bm * 64 + w * 16 + l16;
    int rowc = row < N_NODES ? row : N_NODES - 1;
    const float* xr = x + (size_t)rowc * F_INK;
    short8 a[8];
#pragma unroll
    for (int s = 0; s < 8; s++) {
        const float4* fp = reinterpret_cast<const float4*>(xr + s * 32 + q * 8);
        float4 f0 = fp[0], f1 = fp[1];
        short8 av;
        av[0] = (short)f2bf(f0.x); av[1] = (short)f2bf(f0.y);
        av[2] = (short)f2bf(f0.z); av[3] = (short)f2bf(f0.w);
        av[4] = (short)f2bf(f1.x); av[5] = (short)f2bf(f1.y);
        av[6] = (short)f2bf(f1.z); av[7] = (short)f2bf(f1.w);
        a[s] = av;
    }
    int orow = bm * 64 + w * 16 + q * 4;
#pragma unroll
    for (int bn = 0; bn < 8; bn++) {           // 8 column tiles = 8 heads
        f32x4 acc[4];
#pragma unroll
        for (int t = 0; t < 4; t++) acc[t] = (f32x4){0.f, 0.f, 0.f, 0.f};
#pragma unroll
        for (int s = 0; s < 8; s++) {
#pragma unroll
            for (int t = 0; t < 4; t++) {
                int col = bn * 64 + t * 16 + l16;
                short8 b = *reinterpret_cast<const short8*>(Wp + ((((s << 2) + q) * HC + col) << 3));
                acc[t] = __builtin_amdgcn_mfma_f32_16x16x32_bf16(a[s], b, acc[t], 0, 0, 0);
            }
        }
        float sa0 = 0.f, sa1 = 0.f, sa2 = 0.f, sa3 = 0.f;
        float da0 = 0.f, da1 = 0.f, da2 = 0.f, da3 = 0.f;
#pragma unroll
        for (int t = 0; t < 4; t++) {
            int col = bn * 64 + t * 16 + l16;
            float asc = bf2f(a_s[col]);
            float adc = bf2f(a_d[col]);
            float v0 = acc[t][0], v1 = acc[t][1], v2 = acc[t][2], v3 = acc[t][3];
            sa0 += v0 * asc; da0 += v0 * adc;
            sa1 += v1 * asc; da1 += v1 * adc;
            sa2 += v2 * asc; da2 += v2 * adc;
            sa3 += v3 * asc; da3 += v3 * adc;
            if (orow + 3 < N_NODES) {
                h1f8[(size_t)(orow + 0) * HC + col] = f2fp8(v0);
                h1f8[(size_t)(orow + 1) * HC + col] = f2fp8(v1);
                h1f8[(size_t)(orow + 2) * HC + col] = f2fp8(v2);
                h1f8[(size_t)(orow + 3) * HC + col] = f2fp8(v3);
            } else {
                if (orow + 0 < N_NODES) h1f8[(size_t)(orow + 0) * HC + col] = f2fp8(v0);
                if (orow + 1 < N_NODES) h1f8[(size_t)(orow + 1) * HC + col] = f2fp8(v1);
                if (orow + 2 < N_NODES) h1f8[(size_t)(orow + 2) * HC + col] = f2fp8(v2);
                if (orow + 3 < N_NODES) h1f8[(size_t)(orow + 3) * HC + col] = f2fp8(v3);
            }
        }
#pragma unroll
        for (int m = 1; m < 16; m <<= 1) {
            sa0 += __shfl_xor(sa0, m, 64); sa1 += __shfl_xor(sa1, m, 64);
            sa2 += __shfl_xor(sa2, m, 64); sa3 += __shfl_xor(sa3, m, 64);
            da0 += __shfl_xor(da0, m, 64); da1 += __shfl_xor(da1, m, 64);
            da2 += __shfl_xor(da2, m, 64); da3 += __shfl_xor(da3, m, 64);
        }
        if (l16 < 4) {
            int rr = orow + l16;
            float sav = (l16 == 0) ? sa0 : (l16 == 1) ? sa1 : (l16 == 2) ? sa2 : sa3;
            float dav = (l16 == 0) ? da0 : (l16 == 1) ? da1 : (l16 == 2) ? da2 : da3;
            if (rr < N_NODES) { as1[rr * 8 + bn] = sav; ad1[rr * 8 + bn] = dav; }
        }
    }
}

// ---------------- GEMM2 + alpha2 fused: h2 bf16 [N,40] ----------------
__global__ __launch_bounds__(256) void gemm2_k(const unsigned short* __restrict__ a_in,
                                               const unsigned short* __restrict__ Wp,
                                               const unsigned short* __restrict__ a_s2,
                                               const unsigned short* __restrict__ a_d2,
                                               unsigned short* __restrict__ h2,
                                               float* __restrict__ as2, float* __restrict__ ad2) {
    int w = threadIdx.x >> 6, lane = threadIdx.x & 63;
    int q = lane >> 4, l16 = lane & 15;
    int bm = blockIdx.x;
    int row = bm * 64 + w * 16 + l16;
    int rowc = row < N_NODES ? row : N_NODES - 1;
    const unsigned short* ar = a_in + (size_t)rowc * HC;
    f32x4 acc[3];
#pragma unroll
    for (int t = 0; t < 3; t++) acc[t] = (f32x4){0.f, 0.f, 0.f, 0.f};
#pragma unroll
    for (int s = 0; s < HC / 32; s++) {
        short8 a = *reinterpret_cast<const short8*>(ar + s * 32 + q * 8);
#pragma unroll
        for (int t = 0; t < 3; t++) {
            int col = t * 16 + l16;
            short8 b = *reinterpret_cast<const short8*>(Wp + ((((s << 2) + q) * OUT_P + col) << 3));
            acc[t] = __builtin_amdgcn_mfma_f32_16x16x32_bf16(a, b, acc[t], 0, 0, 0);
        }
    }
    int orow = bm * 64 + w * 16 + q * 4;
    float sa0 = 0.f, sa1 = 0.f, sa2 = 0.f, sa3 = 0.f;
    float da0 = 0.f, da1 = 0.f, da2 = 0.f, da3 = 0.f;
#pragma unroll
    for (int t = 0; t < 3; t++) {
        int col = t * 16 + l16;
        if (col < OUT_C) {
            float asc = bf2f(a_s2[col]);
            float adc = bf2f(a_d2[col]);
            float v0 = acc[t][0], v1 = acc[t][1], v2 = acc[t][2], v3 = acc[t][3];
            sa0 += v0 * asc; da0 += v0 * adc;
            sa1 += v1 * asc; da1 += v1 * adc;
            sa2 += v2 * asc; da2 += v2 * adc;
            sa3 += v3 * asc; da3 += v3 * adc;
#pragma unroll
            for (int r = 0; r < 4; r++) {
                int rr = orow + r;
                if (rr < N_NODES) h2[(size_t)rr * OUT_C + col] = f2bf(acc[t][r]);
            }
        }
    }
#pragma unroll
    for (int m = 1; m < 16; m <<= 1) {
        sa0 += __shfl_xor(sa0, m, 64); sa1 += __shfl_xor(sa1, m, 64);
        sa2 += __shfl_xor(sa2, m, 64); sa3 += __shfl_xor(sa3, m, 64);
        da0 += __shfl_xor(da0, m, 64); da1 += __shfl_xor(da1, m, 64);
        da2 += __shfl_xor(da2, m, 64); da3 += __shfl_xor(da3, m, 64);
    }
    if (l16 < 4) {
        int rr = orow + l16;
        float sav = (l16 == 0) ? sa0 : (l16 == 1) ? sa1 : (l16 == 2) ? sa2 : sa3;
        float dav = (l16 == 0) ? da0 : (l16 == 1) ? da1 : (l16 == 2) ? da2 : da3;
        if (rr < N_NODES) { as2[rr] = sav; ad2[rr] = dav; }
    }
}

// ---------------- CSR build ----------------
__global__ void deg_count(const int* __restrict__ ei, int* __restrict__ deg) {
    int e = blockIdx.x * 256 + threadIdx.x;
    if (e >= N_EDGES) return;
    bool is64 = ei_is64(ei);
    int dst = is64 ? ei[2 * N_EDGES + 2 * e] : ei[N_EDGES + e];
    atomicAdd(&deg[dst], 1);
}
__global__ void scan_block(const int* __restrict__ deg, int* __restrict__ off, int* __restrict__ bsum) {
    __shared__ int s[256];
    int i = blockIdx.x * 256 + threadIdx.x;
    int v = (i < N_NODES) ? deg[i] : 0;
    s[threadIdx.x] = v;
    __syncthreads();
    for (int d = 1; d < 256; d <<= 1) {
        int t = (threadIdx.x >= d) ? s[threadIdx.x - d] : 0;
        __syncthreads();
        s[threadIdx.x] += t;
        __syncthreads();
    }
    if (i < N_NODES) off[i] = s[threadIdx.x] - v;
    if (threadIdx.x == 255) bsum[blockIdx.x] = s[255];
}
__global__ void scan_sums(const int* __restrict__ bsum, int* __restrict__ bscan, int* __restrict__ off, int nb) {
    __shared__ int s[256];
    int v = (threadIdx.x < nb) ? bsum[threadIdx.x] : 0;
    s[threadIdx.x] = v;
    __syncthreads();
    for (int d = 1; d < 256; d <<= 1) {
        int t = (threadIdx.x >= d) ? s[threadIdx.x - d] : 0;
        __syncthreads();
        s[threadIdx.x] += t;
        __syncthreads();
    }
    if (threadIdx.x < nb) bscan[threadIdx.x] = s[threadIdx.x] - v;
    if (threadIdx.x == 255) off[N_NODES] = s[255];
}
__global__ void scan_add(int* __restrict__ off, const int* __restrict__ bscan,
                         int* __restrict__ cursor, int* __restrict__ srcs, int* __restrict__ dsts) {
    int i = blockIdx.x * 256 + threadIdx.x;
    if (i < N_NODES) {
        int v = off[i] + bscan[blockIdx.x];
        off[i] = v;
        srcs[v] = i;
        dsts[v] = i;
        cursor[i] = v + 1;
    }
}
__global__ void scatter_edge(const int* __restrict__ ei, int* __restrict__ cursor,
                             int* __restrict__ srcs, int* __restrict__ dsts) {
    int e = blockIdx.x * 256 + threadIdx.x;
    if (e >= N_EDGES) return;
    bool is64 = ei_is64(ei);
    int src = is64 ? ei[2 * e] : ei[e];
    int dst = is64 ? ei[2 * N_EDGES + 2 * e] : ei[N_EDGES + e];
    int pos = atomicAdd(&cursor[dst], 1);
    srcs[pos] = src;
    dsts[pos] = dst;
}

// ---------------- edge weights, layer 1: wgt1[e][h] bf16 ----------------
__global__ __launch_bounds__(256) void wgt1_k(const int* __restrict__ srcs,
                                              const int* __restrict__ dsts,
                                              const float* __restrict__ as1,
                                              const float* __restrict__ ad1,
                                              uint4* __restrict__ wgt1) {
    int i = blockIdx.x * 256 + threadIdx.x;
    if (i >= E_TOT) return;
    int s = srcs[i], d = dsts[i];
    const float4* sp = reinterpret_cast<const float4*>(as1 + s * 8);
    const float4* dp = reinterpret_cast<const float4*>(ad1 + d * 8);
    float4 sa = sp[0], sb = sp[1], da = dp[0], db = dp[1];
    unsigned int w01 = (unsigned int)f2bf(__expf(lrelu(sa.x + da.x)))
                     | ((unsigned int)f2bf(__expf(lrelu(sa.y + da.y))) << 16);
    unsigned int w23 = (unsigned int)f2bf(__expf(lrelu(sa.z + da.z)))
                     | ((unsigned int)f2bf(__expf(lrelu(sa.w + da.w))) << 16);
    unsigned int w45 = (unsigned int)f2bf(__expf(lrelu(sb.x + db.x)))
                     | ((unsigned int)f2bf(__expf(lrelu(sb.y + db.y))) << 16);
    unsigned int w67 = (unsigned int)f2bf(__expf(lrelu(sb.z + db.z)))
                     | ((unsigned int)f2bf(__expf(lrelu(sb.w + db.w))) << 16);
    wgt1[i] = make_uint4(w01, w23, w45, w67);
}

// ---------------- layer-1 aggregation: one wave per dst, fp8 gather, 8-deep ----------------
#define ACCPK(u, wgt)                                                        \
    {                                                                        \
        f32x2 p0 = __builtin_amdgcn_cvt_pk_f32_fp8((int)(u).x, false);       \
        f32x2 p1 = __builtin_amdgcn_cvt_pk_f32_fp8((int)(u).x, true);        \
        f32x2 p2 = __builtin_amdgcn_cvt_pk_f32_fp8((int)(u).y, false);       \
        f32x2 p3 = __builtin_amdgcn_cvt_pk_f32_fp8((int)(u).y, true);        \
        f32x2 wv = {(wgt), (wgt)};                                           \
        acc01 += wv * p0; acc23 += wv * p1;                                  \
        acc45 += wv * p2; acc67 += wv * p3;                                  \
    }

__global__ __launch_bounds__(256) void agg1_k(const unsigned char* __restrict__ h1f8,
                                              const unsigned short* __restrict__ wgt1,
                                              const int* __restrict__ off,
                                              const int* __restrict__ srcs,
                                              const unsigned short* __restrict__ b1,
                                              unsigned short* __restrict__ out1) {
    int wid = blockIdx.x * 4 + (threadIdx.x >> 6);
    if (wid >= N_NODES) return;
    int lane = threadIdx.x & 63;
    int h = lane >> 3;
    f32x2 acc01 = {0.f, 0.f}, acc23 = {0.f, 0.f}, acc45 = {0.f, 0.f}, acc67 = {0.f, 0.f};
    float sumw = 0.f;
    int e = off[wid], e1 = off[wid + 1];
    for (; e + 8 <= e1; e += 8) {
        int s[8];
        unsigned short wu[8];
        uint2 u[8];
#pragma unroll
        for (int j = 0; j < 8; j++) s[j] = srcs[e + j];
#pragma unroll
        for (int j = 0; j < 8; j++) wu[j] = wgt1[(size_t)(e + j) * 8 + h];
#pragma unroll
        for (int j = 0; j < 8; j++)
            u[j] = reinterpret_cast<const uint2*>(h1f8 + (size_t)s[j] * HC)[lane];
#pragma unroll
        for (int j = 0; j < 8; j++) {
            float wj = bf2f(wu[j]);
            sumw += wj;
            ACCPK(u[j], wj)
        }
    }
    for (; e < e1; e++) {
        int s0 = srcs[e];
        float wj = bf2f(wgt1[(size_t)e * 8 + h]);
        uint2 u0 = reinterpret_cast<const uint2*>(h1f8 + (size_t)s0 * HC)[lane];
        sumw += wj;
        ACCPK(u0, wj)
    }
    float inv = 1.f / sumw;
    uint4 ub = *(reinterpret_cast<const uint4*>(b1) + lane);
    float o0 = fmaxf(acc01[0] * inv + bflo(ub.x), 0.f);
    float o1 = fmaxf(acc01[1] * inv + bfhi(ub.x), 0.f);
    float o2 = fmaxf(acc23[0] * inv + bflo(ub.y), 0.f);
    float o3 = fmaxf(acc23[1] * inv + bfhi(ub.y), 0.f);
    float o4 = fmaxf(acc45[0] * inv + bflo(ub.z), 0.f);
    float o5 = fmaxf(acc45[1] * inv + bfhi(ub.z), 0.f);
    float o6 = fmaxf(acc67[0] * inv + bflo(ub.w), 0.f);
    float o7 = fmaxf(acc67[1] * inv + bfhi(ub.w), 0.f);
    uint4 r;
    r.x = (unsigned int)f2bf(o0) | ((unsigned int)f2bf(o1) << 16);
    r.y = (unsigned int)f2bf(o2) | ((unsigned int)f2bf(o3) << 16);
    r.z = (unsigned int)f2bf(o4) | ((unsigned int)f2bf(o5) << 16);
    r.w = (unsigned int)f2bf(o6) | ((unsigned int)f2bf(o7) << 16);
    *(reinterpret_cast<uint4*>(out1 + (size_t)wid * HC) + lane) = r;
}

// ---------------- layer-2 aggregation + log_softmax (bf16 h2 gather, fp32 out) ----------
__global__ __launch_bounds__(256) void agg2_k(const unsigned short* __restrict__ h2,
                                              const float* __restrict__ as2,
                                              const float* __restrict__ ad2,
                                              const int* __restrict__ off,
                                              const int* __restrict__ srcs,
                                              const unsigned short* __restrict__ b2,
                                              float* __restrict__ outp) {
    int wid = blockIdx.x * 4 + (threadIdx.x >> 6);
    if (wid >= N_NODES) return;
    int lane = threadIdx.x & 63;
    bool act = lane < OUT_C;
    int lclamp = act ? lane : 0;
    float adv = ad2[wid];
    float acc = 0.f, sumw = 0.f;
    int e = off[wid], e1 = off[wid + 1];
    for (; e + 4 <= e1; e += 4) {
        int s0 = srcs[e], s1 = srcs[e + 1], s2 = srcs[e + 2], s3 = srcs[e + 3];
        float A0 = as2[s0], A1 = as2[s1], A2 = as2[s2], A3 = as2[s3];
        float v0 = bf2f(h2[(size_t)s0 * OUT_C + lclamp]);
        float v1 = bf2f(h2[(size_t)s1 * OUT_C + lclamp]);
        float v2 = bf2f(h2[(size_t)s2 * OUT_C + lclamp]);
        float v3 = bf2f(h2[(size_t)s3 * OUT_C + lclamp]);
        float w0 = __expf(lrelu(A0 + adv));
        float w1 = __expf(lrelu(A1 + adv));
        float w2 = __expf(lrelu(A2 + adv));
        float w3 = __expf(lrelu(A3 + adv));
        sumw += (w0 + w1) + (w2 + w3);
        acc += w0 * v0 + w1 * v1 + w2 * v2 + w3 * v3;
    }
    for (; e < e1; e++) {
        int s0 = srcs[e];
        float w0 = __expf(lrelu(as2[s0] + adv));
        sumw += w0;
        acc += w0 * bf2f(h2[(size_t)s0 * OUT_C + lclamp]);
    }
    float o = acc / sumw + bf2f(b2[lclamp]);
    float mval = act ? o : -1e30f;
#pragma unroll
    for (int m = 32; m >= 1; m >>= 1) mval = fmaxf(mval, __shfl_xor(mval, m, 64));
    float ex = act ? __expf(o - mval) : 0.f;
#pragma unroll
    for (int m = 32; m >= 1; m >>= 1) ex += __shfl_xor(ex, m, 64);
    float res = o - mval - __logf(ex);
    if (act) outp[(size_t)wid * OUT_C + lane] = res;
}

extern "C" void kernel_launch(void* const* d_in, const int* in_sizes, int n_in,
                              void* d_out, int out_size, void* d_ws, size_t ws_size,
                              hipStream_t stream) {
    const float* x      = (const float*)d_in[0];
    const int*   ei     = (const int*)d_in[1];
    const float* W1     = (const float*)d_in[2];
    const float* as1raw = (const float*)d_in[3];
    const float* ad1raw = (const float*)d_in[4];
    const float* b1raw  = (const float*)d_in[5];
    const float* W2     = (const float*)d_in[6];
    const float* as2raw = (const float*)d_in[7];
    const float* ad2raw = (const float*)d_in[8];
    const float* b2raw  = (const float*)d_in[9];
    float* out = (float*)d_out;

    char* p = (char*)d_ws;
    auto alloc = [&](size_t bytes) -> char* {
        char* r = p;
        p += (bytes + 255) & ~(size_t)255;
        return r;
    };
    unsigned short* s1c  = (unsigned short*)alloc(512 * 2);
    unsigned short* d1c  = (unsigned short*)alloc(512 * 2);
    unsigned short* b1c  = (unsigned short*)alloc(512 * 2);
    unsigned short* s2c  = (unsigned short*)alloc(OUT_C * 2);
    unsigned short* d2c  = (unsigned short*)alloc(OUT_C * 2);
    unsigned short* b2c  = (unsigned short*)alloc(OUT_C * 2);
    unsigned char*  h1f8 = (unsigned char*)alloc((size_t)N_NODES * HC);        // 25.6 MB
    unsigned short* out1 = (unsigned short*)alloc((size_t)N_NODES * HC * 2);   // 51.2 MB
    unsigned short* h2   = (unsigned short*)alloc((size_t)N_NODES * OUT_C * 2);// 4 MB
    float* as1  = (float*)alloc((size_t)N_NODES * 8 * 4);
    float* ad1  = (float*)alloc((size_t)N_NODES * 8 * 4);
    float* as2  = (float*)alloc((size_t)N_NODES * 4);
    float* ad2  = (float*)alloc((size_t)N_NODES * 4);
    int* deg    = (int*)alloc((size_t)N_NODES * 4);
    int* off    = (int*)alloc((size_t)(N_NODES + 1) * 4);
    int* cursor = (int*)alloc((size_t)N_NODES * 4);
    int* srcs   = (int*)alloc((size_t)E_TOT * 4);
    int* dsts   = (int*)alloc((size_t)E_TOT * 4);
    unsigned short* wgt1 = (unsigned short*)alloc((size_t)E_TOT * 8 * 2);      // 13.6 MB
    unsigned short* W1p = (unsigned short*)alloc((size_t)F_INK * HC * 2);
    unsigned short* W2p = (unsigned short*)alloc((size_t)HC * OUT_P * 2);
    int* bsum  = (int*)alloc(256 * 4);
    int* bscan = (int*)alloc(256 * 4);
    (void)ws_size; (void)in_sizes; (void)n_in; (void)out_size;

    const int NB = (N_NODES + 255) / 256;  // 196

    pack_w1<<<(F_INK * HC + 255) / 256, 256, 0, stream>>>(W1, W1p);
    pack_w2<<<(HC * OUT_P + 255) / 256, 256, 0, stream>>>(W2, W2p);
    canon_small<<<NB, 256, 0, stream>>>(as1raw, ad1raw, b1raw, as2raw, ad2raw, b2raw,
                                        s1c, d1c, b1c, s2c, d2c, b2c, deg);
    deg_count<<<(N_EDGES + 255) / 256, 256, 0, stream>>>(ei, deg);
    scan_block<<<NB, 256, 0, stream>>>(deg, off, bsum);
    scan_sums<<<1, 256, 0, stream>>>(bsum, bscan, off, NB);
    scan_add<<<NB, 256, 0, stream>>>(off, bscan, cursor, srcs, dsts);
    scatter_edge<<<(N_EDGES + 255) / 256, 256, 0, stream>>>(ei, cursor, srcs, dsts);
    gemm1_k<<<(N_NODES + 63) / 64, 256, 0, stream>>>(x, W1p, s1c, d1c, h1f8, as1, ad1);
    wgt1_k<<<(E_TOT + 255) / 256, 256, 0, stream>>>(srcs, dsts, as1, ad1, (uint4*)wgt1);
    agg1_k<<<(N_NODES + 3) / 4, 256, 0, stream>>>(h1f8, wgt1, off, srcs, b1c, out1);
    gemm2_k<<<(N_NODES + 63) / 64, 256, 0, stream>>>(out1, W2p, s2c, d2c, h2, as2, ad2);
    agg2_k<<<(N_NODES + 3) / 4, 256, 0, stream>>>(h2, as2, ad2, off, srcs, b2c, out);
}